// Round 4
// baseline (209.997 us; speedup 1.0000x reference)
//
#include <hip/hip_runtime.h>
#include <math.h>

constexpr int kB = 16, kC = 128, kHW = 4096, kL = 512, kND = 256, kG = 32;
constexpr float kEps = 1e-6f;
constexpr float kScale = 0.08838834764831845f;  // 128^-0.5

typedef short sv8 __attribute__((ext_vector_type(8)));
typedef float f32x16 __attribute__((ext_vector_type(16)));

static __device__ __forceinline__ unsigned short f2bf(float f) {
    unsigned int u = __builtin_bit_cast(unsigned int, f);
    u += 0x7fffu + ((u >> 16) & 1u);
    return (unsigned short)(u >> 16);
}
static __device__ __forceinline__ float bf2f(unsigned short s) {
    unsigned int u = ((unsigned int)s) << 16;
    return __builtin_bit_cast(float, u);
}

// ---------------- Kernel 1: GroupNorm statistics ----------------
__global__ __launch_bounds__(256) void gn_stats_k(const float* __restrict__ x,
                                                  float* __restrict__ stats) {
    int bg = blockIdx.x;
    const float4* p4 = (const float4*)(x + (size_t)bg * 4 * kHW);
    int tid = threadIdx.x;
    float s = 0.f, ss = 0.f;
    for (int i = tid; i < 4096; i += 256) {
        float4 v = p4[i];
        s  += (v.x + v.y) + (v.z + v.w);
        ss += (v.x * v.x + v.y * v.y) + (v.z * v.z + v.w * v.w);
    }
#pragma unroll
    for (int off = 1; off < 64; off <<= 1) {
        s  += __shfl_xor(s, off, 64);
        ss += __shfl_xor(ss, off, 64);
    }
    __shared__ float red[8];
    int wid = tid >> 6;
    if ((tid & 63) == 0) { red[wid] = s; red[wid + 4] = ss; }
    __syncthreads();
    if (tid == 0) {
        float S  = (red[0] + red[1]) + (red[2] + red[3]);
        float SS = (red[4] + red[5]) + (red[6] + red[7]);
        float mean = S * (1.f / 16384.f);
        float var  = SS * (1.f / 16384.f) - mean * mean;
        stats[bg * 2]     = mean;
        stats[bg * 2 + 1] = rsqrtf(var + kEps);
    }
}

// ---------------- Kernel 1b: proj_w -> bf16 ----------------
__global__ __launch_bounds__(256) void prep_k(const float* __restrict__ w,
                                              unsigned short* __restrict__ wb) {
    int i = (blockIdx.x * 256 + threadIdx.x) * 4;
    float4 v = *(const float4*)(w + i);
    wb[i + 0] = f2bf(v.x); wb[i + 1] = f2bf(v.y);
    wb[i + 2] = f2bf(v.z); wb[i + 3] = f2bf(v.w);
}

// ---------------- Kernel 2: kv = silu(nd) @ nd_w^T + nd_b (bf16 + bf16^T) ----
__global__ __launch_bounds__(256) void kv_k(const float* __restrict__ nd,
                                            const float* __restrict__ nd_w,
                                            const float* __restrict__ nd_b,
                                            unsigned short* __restrict__ kv_bf,
                                            unsigned short* __restrict__ kvT_bf) {
    __shared__ float s_lds[8][256];
    __shared__ float w_lds[128][68];
    __shared__ float t_lds[8][129];
    int b = blockIdx.y;
    int l0 = blockIdx.x * 8;
    int tid = threadIdx.x;
    const float4* ndp = (const float4*)(nd + ((size_t)b * kL + l0) * kND);
#pragma unroll
    for (int r = 0; r < 2; r++) {
        int idx = tid + r * 256;
        int row = idx >> 6;
        int c4 = idx & 63;
        float4 v = ndp[row * 64 + c4];
        v.x = v.x / (1.f + __expf(-v.x));
        v.y = v.y / (1.f + __expf(-v.y));
        v.z = v.z / (1.f + __expf(-v.z));
        v.w = v.w / (1.f + __expf(-v.w));
        *(float4*)&s_lds[row][c4 * 4] = v;
    }
    float acc[4] = {0.f, 0.f, 0.f, 0.f};
    int lr = tid >> 5;
    int oq = tid & 31;
    for (int d0 = 0; d0 < kND; d0 += 64) {
        __syncthreads();
#pragma unroll
        for (int r = 0; r < 8; r++) {
            int idx = tid + r * 256;
            int row = idx >> 4;
            int c4 = idx & 15;
            float4 v = ((const float4*)(nd_w + (size_t)row * kND + d0))[c4];
            *(float4*)&w_lds[row][c4 * 4] = v;
        }
        __syncthreads();
        for (int dd = 0; dd < 64; dd += 4) {
            float4 sv = *(const float4*)&s_lds[lr][d0 + dd];
#pragma unroll
            for (int j = 0; j < 4; j++) {
                float4 wv = *(const float4*)&w_lds[oq + 32 * j][dd];
                acc[j] += sv.x * wv.x + sv.y * wv.y + sv.z * wv.z + sv.w * wv.w;
            }
        }
    }
#pragma unroll
    for (int j = 0; j < 4; j++) {
        int o = oq + 32 * j;
        float vout = acc[j] + nd_b[o];
        kv_bf[((size_t)b * kL + l0 + lr) * kC + o] = f2bf(vout);
        t_lds[lr][o] = vout;
    }
    __syncthreads();
    {
        int o = tid >> 1, lh = (tid & 1) * 4;
        unsigned long long pk = 0;
#pragma unroll
        for (int i = 0; i < 4; i++)
            pk |= (unsigned long long)f2bf(t_lds[lh + i][o]) << (16 * i);
        *(unsigned long long*)(kvT_bf + ((size_t)b * kC + o) * kL + l0 + lh) = pk;
    }
}

// ---------------- Kernel 3: q = (GN(x))^T @ q_w^T + q_b  (bf16 MFMA) -------
__global__ __launch_bounds__(256) void qproj_k(const float* __restrict__ x,
                                               const float* __restrict__ stats,
                                               const float* __restrict__ gamma,
                                               const float* __restrict__ beta,
                                               const float* __restrict__ q_w,
                                               const float* __restrict__ q_b,
                                               unsigned short* __restrict__ q_bf) {
    __shared__ __align__(16) unsigned short smem[17408];  // [128][136] bf16
    __shared__ float gab[256];                            // ga[128], be[128]
    const int b = blockIdx.y;
    const int n0 = blockIdx.x * 128;
    const int tid = threadIdx.x;
    const int wave = tid >> 6, lane = tid & 63;
    const int lrow = lane & 31, hi = lane >> 5;

    if (tid < 128) {
        float mean = stats[(b * kG + (tid >> 2)) * 2];
        float rstd = stats[(b * kG + (tid >> 2)) * 2 + 1];
        float ga = gamma[tid] * rstd;
        gab[tid] = ga;
        gab[128 + tid] = beta[tid] - mean * ga;
    }
    // stage q_w as bf16 [o][c], padded stride 136
#pragma unroll
    for (int r = 0; r < 16; r++) {
        int idx = tid + r * 256;            // 4096 float4 = 128x32
        int row = idx >> 5, c4 = idx & 31;
        float4 v = ((const float4*)q_w)[idx];
        unsigned int lo = (unsigned int)f2bf(v.x) | ((unsigned int)f2bf(v.y) << 16);
        unsigned int h2 = (unsigned int)f2bf(v.z) | ((unsigned int)f2bf(v.w) << 16);
        *(uint2*)&smem[row * 136 + c4 * 4] = make_uint2(lo, h2);
    }
    __syncthreads();

    // A fragments: hn[n][c] with GN fused, straight from global
    sv8 qa[8];
    {
        const float* xp = x + (size_t)b * kC * kHW + n0 + wave * 32 + lrow;
#pragma unroll
        for (int kc = 0; kc < 8; kc++) {
            int cb = kc * 16 + hi * 8;
            float4 g0 = *(const float4*)&gab[cb];
            float4 g1 = *(const float4*)&gab[cb + 4];
            float4 e0 = *(const float4*)&gab[128 + cb];
            float4 e1 = *(const float4*)&gab[128 + cb + 4];
            sv8 a;
            a[0] = (short)f2bf(xp[(size_t)(cb + 0) * kHW] * g0.x + e0.x);
            a[1] = (short)f2bf(xp[(size_t)(cb + 1) * kHW] * g0.y + e0.y);
            a[2] = (short)f2bf(xp[(size_t)(cb + 2) * kHW] * g0.z + e0.z);
            a[3] = (short)f2bf(xp[(size_t)(cb + 3) * kHW] * g0.w + e0.w);
            a[4] = (short)f2bf(xp[(size_t)(cb + 4) * kHW] * g1.x + e1.x);
            a[5] = (short)f2bf(xp[(size_t)(cb + 5) * kHW] * g1.y + e1.y);
            a[6] = (short)f2bf(xp[(size_t)(cb + 6) * kHW] * g1.z + e1.z);
            a[7] = (short)f2bf(xp[(size_t)(cb + 7) * kHW] * g1.w + e1.w);
            qa[kc] = a;
        }
    }

    f32x16 dacc[4];
#pragma unroll
    for (int ot = 0; ot < 4; ot++)
#pragma unroll
        for (int r = 0; r < 16; r++) dacc[ot][r] = 0.f;
#pragma unroll
    for (int ot = 0; ot < 4; ot++) {
        const unsigned short* brow = smem + (ot * 32 + lrow) * 136 + hi * 8;
#pragma unroll
        for (int kc = 0; kc < 8; kc++)
            dacc[ot] = __builtin_amdgcn_mfma_f32_32x32x16_bf16(
                           qa[kc], *(const sv8*)(brow + kc * 16), dacc[ot], 0, 0, 0);
    }
    __syncthreads();   // all B-reads done; reuse smem as q[n][o] transpose

#pragma unroll
    for (int ot = 0; ot < 4; ot++) {
        int o = ot * 32 + lrow;
        float qb = q_b[o];
#pragma unroll
        for (int r = 0; r < 16; r++) {
            int n_loc = wave * 32 + (r & 3) + 8 * (r >> 2) + 4 * hi;
            smem[n_loc * 136 + o] = f2bf((dacc[ot][r] + qb) * kScale);
        }
    }
    __syncthreads();
#pragma unroll
    for (int r = 0; r < 8; r++) {
        int idx = tid + r * 256;            // 2048 uint4 = 128 rows x 16
        int n = idx >> 4, ch = idx & 15;
        *(uint4*)(q_bf + ((size_t)b * kHW + n0 + n) * kC + ch * 8) =
            *(const uint4*)&smem[n * 136 + ch * 8];
    }
}

// ---------------- Kernel 4: MFMA attention + proj + residual ----------------
// Block: 128 Q-rows x 1 batch, 4 waves x 32 rows. 3 blocks/CU (48 KB LDS).
// XOR-swizzled LDS tiles (byte ^= (row&7)<<4); register-prefetch pipeline.
__global__ __launch_bounds__(256, 3) void attn_k(
    const unsigned short* __restrict__ qb,    // [B][HW][C] bf16, pre-scaled
    const unsigned short* __restrict__ kvb,   // [B][L][C] bf16
    const unsigned short* __restrict__ kvtb,  // [B][C][L] bf16
    const unsigned short* __restrict__ pwb,   // [C][C] bf16 (o-major)
    const float* __restrict__ proj_b,
    const float* __restrict__ x,
    float* __restrict__ out)
{
    __shared__ __align__(16) unsigned short smem[24576];  // 49,152 B
    char* base = (char*)smem;
    // bytes [0,16384):      kv_sw  rows l=0..63,  256 B/row, ^((l&7)<<4)
    // bytes [16384,32768):  kvt_sw rows c=0..127, 128 B/row, ^((c&7)<<4)
    // bytes [32768,49152):  p_sw   per-wave [32 n][64 l], 128 B/row, ^((n&7)<<4)
    // epilogue: o_lds shorts [0, 128*136) stride 136 (aliases; barrier-guarded)

    const int b = blockIdx.y;
    const int n0 = blockIdx.x * 128;
    const int tid = threadIdx.x;
    const int wave = tid >> 6;
    const int lane = tid & 63;
    const int lrow = lane & 31;
    const int hi = lane >> 5;
    const int swz_l = (lrow & 7) << 4;

    // Q A-fragments
    sv8 qa[8];
    {
        const unsigned short* qrow =
            qb + ((size_t)b * kHW + n0 + wave * 32 + lrow) * kC + hi * 8;
#pragma unroll
        for (int kc = 0; kc < 8; kc++)
            qa[kc] = *(const sv8*)(qrow + kc * 16);
    }

    f32x16 oacc[4];
#pragma unroll
    for (int ct = 0; ct < 4; ct++)
#pragma unroll
        for (int r = 0; r < 16; r++) oacc[ct][r] = 0.f;
    float rsum[16];
#pragma unroll
    for (int r = 0; r < 16; r++) rsum[r] = 0.f;

    char* pbase = base + 32768 + wave * 4096;

    // ---- staging helpers (reg prefetch -> swizzled LDS) ----
    uint4 pf[8];
    const uint4* gkv  = (const uint4*)(kvb  + (size_t)b * kL * kC);
    const uint4* gkvt = (const uint4*)(kvtb + (size_t)b * kC * kL);

    auto issue = [&](int l0) {
        const uint4* g = gkv + (size_t)l0 * (kC / 8);
#pragma unroll
        for (int r = 0; r < 4; r++) pf[r] = g[tid + r * 256];
        const uint4* gt = gkvt + (l0 >> 3);
#pragma unroll
        for (int r = 0; r < 4; r++) {
            int idx = tid + r * 256;
            pf[4 + r] = gt[(idx >> 3) * (kL / 8) + (idx & 7)];
        }
    };
    auto commit = [&]() {
#pragma unroll
        for (int r = 0; r < 4; r++) {
            int idx = tid + r * 256;
            int row = idx >> 4, ch = idx & 15;
            *(uint4*)(base + ((row * 256 + ch * 16) ^ ((row & 7) << 4))) = pf[r];
        }
#pragma unroll
        for (int r = 0; r < 4; r++) {
            int idx = tid + r * 256;
            int row = idx >> 3, ch = idx & 7;
            *(uint4*)(base + 16384 + ((row * 128 + ch * 16) ^ ((row & 7) << 4))) = pf[4 + r];
        }
    };

    issue(0);
    commit();

    for (int t = 0; t < 8; t++) {
        __syncthreads();                       // tile t LDS writes visible
        if (t < 7) issue((t + 1) << 6);        // prefetch tile t+1 (in flight)

        // ---- QK^T + exp + P-write ----
#pragma unroll
        for (int ls = 0; ls < 2; ls++) {
            f32x16 s;
#pragma unroll
            for (int r = 0; r < 16; r++) s[r] = 0.f;
            const char* rowp = base + (ls * 32 + lrow) * 256;
            __builtin_amdgcn_s_setprio(1);
#pragma unroll
            for (int kc = 0; kc < 8; kc++)
                s = __builtin_amdgcn_mfma_f32_32x32x16_bf16(
                        qa[kc], *(const sv8*)(rowp + ((kc * 32 + hi * 16) ^ swz_l)),
                        s, 0, 0, 0);
            __builtin_amdgcn_s_setprio(0);
#pragma unroll
            for (int r = 0; r < 16; r++) {
                float p = __expf(s[r]);
                rsum[r] += p;
                int n = (r & 3) + 8 * (r >> 2) + 4 * hi;
                *(unsigned short*)(pbase + n * 128 +
                    (((ls * 32 + lrow) * 2) ^ ((n & 7) << 4))) = f2bf(p);
            }
        }
        // ---- PV ----
        sv8 pa[4];
#pragma unroll
        for (int kk = 0; kk < 4; kk++)
            pa[kk] = *(const sv8*)(pbase + lrow * 128 + ((kk * 32 + hi * 16) ^ swz_l));
        __builtin_amdgcn_s_setprio(1);
#pragma unroll
        for (int ct = 0; ct < 4; ct++) {
            const char* rowp = base + 16384 + (ct * 32 + lrow) * 128;
#pragma unroll
            for (int kk = 0; kk < 4; kk++)
                oacc[ct] = __builtin_amdgcn_mfma_f32_32x32x16_bf16(
                               pa[kk], *(const sv8*)(rowp + ((kk * 32 + hi * 16) ^ swz_l)),
                               oacc[ct], 0, 0, 0);
        }
        __builtin_amdgcn_s_setprio(0);

        __syncthreads();                       // tile t reads done
        if (t < 7) commit();                   // write tile t+1 into LDS
    }

    // softmax denominators: reduce across the 32 l-columns
#pragma unroll
    for (int r = 0; r < 16; r++) {
        float v = rsum[r];
        v += __shfl_xor(v, 1, 64);
        v += __shfl_xor(v, 2, 64);
        v += __shfl_xor(v, 4, 64);
        v += __shfl_xor(v, 8, 64);
        v += __shfl_xor(v, 16, 64);
        rsum[r] = 1.f / v;
    }

    unsigned short* o_lds = smem;              // [128][136], aliases pool
    __syncthreads();
#pragma unroll
    for (int ct = 0; ct < 4; ct++)
#pragma unroll
        for (int r = 0; r < 16; r++) {
            int n = wave * 32 + (r & 3) + 8 * (r >> 2) + 4 * hi;
            o_lds[n * 136 + ct * 32 + lrow] = f2bf(oacc[ct][r] * rsum[r]);
        }
    // proj: D[n][o] = O[n][c] * pw[o][c]
    sv8 oa[8];
    {
        const unsigned short* orow = o_lds + (wave * 32 + lrow) * 136 + hi * 8;
#pragma unroll
        for (int kc = 0; kc < 8; kc++) oa[kc] = *(const sv8*)(orow + kc * 16);
    }
    f32x16 dacc[4];
#pragma unroll
    for (int ot = 0; ot < 4; ot++)
#pragma unroll
        for (int r = 0; r < 16; r++) dacc[ot][r] = 0.f;
#pragma unroll
    for (int ot = 0; ot < 4; ot++) {
        const unsigned short* brow = pwb + (ot * 32 + lrow) * kC + hi * 8;
#pragma unroll
        for (int kc = 0; kc < 8; kc++)
            dacc[ot] = __builtin_amdgcn_mfma_f32_32x32x16_bf16(
                           oa[kc], *(const sv8*)(brow + kc * 16), dacc[ot], 0, 0, 0);
    }
#pragma unroll
    for (int ot = 0; ot < 4; ot++)
#pragma unroll
        for (int r = 0; r < 16; r++) {
            int n = wave * 32 + (r & 3) + 8 * (r >> 2) + 4 * hi;
            o_lds[n * 136 + ot * 32 + lrow] = f2bf(dacc[ot][r]);
        }
    __syncthreads();
#pragma unroll 4
    for (int it = 0; it < 64; it++) {
        int idx = it * 256 + tid;
        int o = idx >> 7, n = idx & 127;
        size_t gi = ((size_t)b * kC + o) * kHW + n0 + n;
        out[gi] = bf2f(o_lds[n * 136 + o]) + proj_b[o] + x[gi];
    }
}

extern "C" void kernel_launch(void* const* d_in, const int* in_sizes, int n_in,
                              void* d_out, int out_size, void* d_ws, size_t ws_size,
                              hipStream_t stream) {
    const float* x      = (const float*)d_in[0];
    const float* nd     = (const float*)d_in[1];
    const float* gamma  = (const float*)d_in[2];
    const float* beta   = (const float*)d_in[3];
    const float* q_w    = (const float*)d_in[4];
    const float* q_b    = (const float*)d_in[5];
    const float* nd_w   = (const float*)d_in[6];
    const float* nd_b   = (const float*)d_in[7];
    const float* proj_w = (const float*)d_in[8];
    const float* proj_b = (const float*)d_in[9];
    float* out = (float*)d_out;

    float* stats          = (float*)d_ws;                  // 1024 f32
    unsigned short* pwb   = (unsigned short*)(stats + 1024);       // 16384
    unsigned short* kv_bf = pwb + 16384;                   // 1,048,576
    unsigned short* kvT_bf = kv_bf + (size_t)kB * kL * kC; // 1,048,576
    unsigned short* q_bf  = kvT_bf + (size_t)kB * kL * kC; // 8,388,608

    gn_stats_k<<<dim3(kB * kG), dim3(256), 0, stream>>>(x, stats);
    prep_k<<<dim3(16), dim3(256), 0, stream>>>(proj_w, pwb);
    kv_k<<<dim3(kL / 8, kB), dim3(256), 0, stream>>>(nd, nd_w, nd_b, kv_bf, kvT_bf);
    qproj_k<<<dim3(kHW / 128, kB), dim3(256), 0, stream>>>(x, stats, gamma, beta, q_w, q_b, q_bf);
    attn_k<<<dim3(kHW / 128, kB), dim3(256), 0, stream>>>(q_bf, kv_bf, kvT_bf, pwb,
                                                          proj_b, x, out);
}

// Round 5
// 138.492 us; speedup vs baseline: 1.5163x; 1.5163x over previous
//
#include <hip/hip_runtime.h>
#include <math.h>

constexpr int kB = 16, kC = 128, kHW = 4096, kL = 512, kND = 256, kG = 32;
constexpr float kEps = 1e-6f;
constexpr float kScale = 0.08838834764831845f;  // 128^-0.5

typedef short sv8 __attribute__((ext_vector_type(8)));
typedef float f32x16 __attribute__((ext_vector_type(16)));

static __device__ __forceinline__ unsigned short f2bf(float f) {
    unsigned int u = __builtin_bit_cast(unsigned int, f);
    u += 0x7fffu + ((u >> 16) & 1u);
    return (unsigned short)(u >> 16);
}
static __device__ __forceinline__ float bf2f(unsigned short s) {
    unsigned int u = ((unsigned int)s) << 16;
    return __builtin_bit_cast(float, u);
}

// ---------------- Kernel 1: GroupNorm statistics ----------------
__global__ __launch_bounds__(256) void gn_stats_k(const float* __restrict__ x,
                                                  float* __restrict__ stats) {
    int bg = blockIdx.x;
    const float4* p4 = (const float4*)(x + (size_t)bg * 4 * kHW);
    int tid = threadIdx.x;
    float s = 0.f, ss = 0.f;
    for (int i = tid; i < 4096; i += 256) {
        float4 v = p4[i];
        s  += (v.x + v.y) + (v.z + v.w);
        ss += (v.x * v.x + v.y * v.y) + (v.z * v.z + v.w * v.w);
    }
#pragma unroll
    for (int off = 1; off < 64; off <<= 1) {
        s  += __shfl_xor(s, off, 64);
        ss += __shfl_xor(ss, off, 64);
    }
    __shared__ float red[8];
    int wid = tid >> 6;
    if ((tid & 63) == 0) { red[wid] = s; red[wid + 4] = ss; }
    __syncthreads();
    if (tid == 0) {
        float S  = (red[0] + red[1]) + (red[2] + red[3]);
        float SS = (red[4] + red[5]) + (red[6] + red[7]);
        float mean = S * (1.f / 16384.f);
        float var  = SS * (1.f / 16384.f) - mean * mean;
        stats[bg * 2]     = mean;
        stats[bg * 2 + 1] = rsqrtf(var + kEps);
    }
}

// ---------------- Kernel 1b: proj_w -> bf16 ----------------
__global__ __launch_bounds__(256) void prep_k(const float* __restrict__ w,
                                              unsigned short* __restrict__ wb) {
    int i = (blockIdx.x * 256 + threadIdx.x) * 4;
    float4 v = *(const float4*)(w + i);
    wb[i + 0] = f2bf(v.x); wb[i + 1] = f2bf(v.y);
    wb[i + 2] = f2bf(v.z); wb[i + 3] = f2bf(v.w);
}

// ---------------- Kernel 2: kv = silu(nd) @ nd_w^T + nd_b (bf16 + bf16^T) ----
__global__ __launch_bounds__(256) void kv_k(const float* __restrict__ nd,
                                            const float* __restrict__ nd_w,
                                            const float* __restrict__ nd_b,
                                            unsigned short* __restrict__ kv_bf,
                                            unsigned short* __restrict__ kvT_bf) {
    __shared__ float s_lds[8][256];
    __shared__ float w_lds[128][68];
    __shared__ float t_lds[8][129];
    int b = blockIdx.y;
    int l0 = blockIdx.x * 8;
    int tid = threadIdx.x;
    const float4* ndp = (const float4*)(nd + ((size_t)b * kL + l0) * kND);
#pragma unroll
    for (int r = 0; r < 2; r++) {
        int idx = tid + r * 256;
        int row = idx >> 6;
        int c4 = idx & 63;
        float4 v = ndp[row * 64 + c4];
        v.x = v.x / (1.f + __expf(-v.x));
        v.y = v.y / (1.f + __expf(-v.y));
        v.z = v.z / (1.f + __expf(-v.z));
        v.w = v.w / (1.f + __expf(-v.w));
        *(float4*)&s_lds[row][c4 * 4] = v;
    }
    float acc[4] = {0.f, 0.f, 0.f, 0.f};
    int lr = tid >> 5;
    int oq = tid & 31;
    for (int d0 = 0; d0 < kND; d0 += 64) {
        __syncthreads();
#pragma unroll
        for (int r = 0; r < 8; r++) {
            int idx = tid + r * 256;
            int row = idx >> 4;
            int c4 = idx & 15;
            float4 v = ((const float4*)(nd_w + (size_t)row * kND + d0))[c4];
            *(float4*)&w_lds[row][c4 * 4] = v;
        }
        __syncthreads();
        for (int dd = 0; dd < 64; dd += 4) {
            float4 sv = *(const float4*)&s_lds[lr][d0 + dd];
#pragma unroll
            for (int j = 0; j < 4; j++) {
                float4 wv = *(const float4*)&w_lds[oq + 32 * j][dd];
                acc[j] += sv.x * wv.x + sv.y * wv.y + sv.z * wv.z + sv.w * wv.w;
            }
        }
    }
#pragma unroll
    for (int j = 0; j < 4; j++) {
        int o = oq + 32 * j;
        float vout = acc[j] + nd_b[o];
        kv_bf[((size_t)b * kL + l0 + lr) * kC + o] = f2bf(vout);
        t_lds[lr][o] = vout;
    }
    __syncthreads();
    {
        int o = tid >> 1, lh = (tid & 1) * 4;
        unsigned long long pk = 0;
#pragma unroll
        for (int i = 0; i < 4; i++)
            pk |= (unsigned long long)f2bf(t_lds[lh + i][o]) << (16 * i);
        *(unsigned long long*)(kvT_bf + ((size_t)b * kC + o) * kL + l0 + lh) = pk;
    }
}

// ---------------- Kernel 3: q = (GN(x))^T @ q_w^T + q_b  (bf16 MFMA) -------
__global__ __launch_bounds__(256) void qproj_k(const float* __restrict__ x,
                                               const float* __restrict__ stats,
                                               const float* __restrict__ gamma,
                                               const float* __restrict__ beta,
                                               const float* __restrict__ q_w,
                                               const float* __restrict__ q_b,
                                               unsigned short* __restrict__ q_bf) {
    __shared__ __align__(16) unsigned short smem[17408];  // [128][136] bf16
    __shared__ float gab[256];                            // ga[128], be[128]
    const int b = blockIdx.y;
    const int n0 = blockIdx.x * 128;
    const int tid = threadIdx.x;
    const int wave = tid >> 6, lane = tid & 63;
    const int lrow = lane & 31, hi = lane >> 5;

    if (tid < 128) {
        float mean = stats[(b * kG + (tid >> 2)) * 2];
        float rstd = stats[(b * kG + (tid >> 2)) * 2 + 1];
        float ga = gamma[tid] * rstd;
        gab[tid] = ga;
        gab[128 + tid] = beta[tid] - mean * ga;
    }
    // stage q_w as bf16 [o][c], padded stride 136
#pragma unroll
    for (int r = 0; r < 16; r++) {
        int idx = tid + r * 256;            // 4096 float4 = 128x32
        int row = idx >> 5, c4 = idx & 31;
        float4 v = ((const float4*)q_w)[idx];
        unsigned int lo = (unsigned int)f2bf(v.x) | ((unsigned int)f2bf(v.y) << 16);
        unsigned int h2 = (unsigned int)f2bf(v.z) | ((unsigned int)f2bf(v.w) << 16);
        *(uint2*)&smem[row * 136 + c4 * 4] = make_uint2(lo, h2);
    }
    __syncthreads();

    // A fragments: hn[n][c] with GN fused, straight from global
    sv8 qa[8];
    {
        const float* xp = x + (size_t)b * kC * kHW + n0 + wave * 32 + lrow;
#pragma unroll
        for (int kc = 0; kc < 8; kc++) {
            int cb = kc * 16 + hi * 8;
            float4 g0 = *(const float4*)&gab[cb];
            float4 g1 = *(const float4*)&gab[cb + 4];
            float4 e0 = *(const float4*)&gab[128 + cb];
            float4 e1 = *(const float4*)&gab[128 + cb + 4];
            sv8 a;
            a[0] = (short)f2bf(xp[(size_t)(cb + 0) * kHW] * g0.x + e0.x);
            a[1] = (short)f2bf(xp[(size_t)(cb + 1) * kHW] * g0.y + e0.y);
            a[2] = (short)f2bf(xp[(size_t)(cb + 2) * kHW] * g0.z + e0.z);
            a[3] = (short)f2bf(xp[(size_t)(cb + 3) * kHW] * g0.w + e0.w);
            a[4] = (short)f2bf(xp[(size_t)(cb + 4) * kHW] * g1.x + e1.x);
            a[5] = (short)f2bf(xp[(size_t)(cb + 5) * kHW] * g1.y + e1.y);
            a[6] = (short)f2bf(xp[(size_t)(cb + 6) * kHW] * g1.z + e1.z);
            a[7] = (short)f2bf(xp[(size_t)(cb + 7) * kHW] * g1.w + e1.w);
            qa[kc] = a;
        }
    }

    f32x16 dacc[4];
#pragma unroll
    for (int ot = 0; ot < 4; ot++)
#pragma unroll
        for (int r = 0; r < 16; r++) dacc[ot][r] = 0.f;
#pragma unroll
    for (int ot = 0; ot < 4; ot++) {
        const unsigned short* brow = smem + (ot * 32 + lrow) * 136 + hi * 8;
#pragma unroll
        for (int kc = 0; kc < 8; kc++)
            dacc[ot] = __builtin_amdgcn_mfma_f32_32x32x16_bf16(
                           qa[kc], *(const sv8*)(brow + kc * 16), dacc[ot], 0, 0, 0);
    }
    __syncthreads();   // all B-reads done; reuse smem as q[n][o] transpose

#pragma unroll
    for (int ot = 0; ot < 4; ot++) {
        int o = ot * 32 + lrow;
        float qb = q_b[o];
#pragma unroll
        for (int r = 0; r < 16; r++) {
            int n_loc = wave * 32 + (r & 3) + 8 * (r >> 2) + 4 * hi;
            smem[n_loc * 136 + o] = f2bf((dacc[ot][r] + qb) * kScale);
        }
    }
    __syncthreads();
#pragma unroll
    for (int r = 0; r < 8; r++) {
        int idx = tid + r * 256;            // 2048 uint4 = 128 rows x 16
        int n = idx >> 4, ch = idx & 15;
        *(uint4*)(q_bf + ((size_t)b * kHW + n0 + n) * kC + ch * 8) =
            *(const uint4*)&smem[n * 136 + ch * 8];
    }
}

// ---------------- Kernel 4: MFMA attention + proj + residual ----------------
// Block: 128 Q-rows x 1 batch, 4 waves x 32 rows. NO kv LDS staging: the
// per-batch kv/kvT (256 KB) is L2-resident, and MFMA B-fragments are
// contiguous 16B row-reads -> load them straight from global. Main loop is
// barrier-free (P buffer is per-wave). LDS = 34.8 KB (P pool + epilogue).
__global__ __launch_bounds__(256) void attn_k(
    const unsigned short* __restrict__ qb,    // [B][HW][C] bf16, pre-scaled
    const unsigned short* __restrict__ kvb,   // [B][L][C] bf16
    const unsigned short* __restrict__ kvtb,  // [B][C][L] bf16
    const unsigned short* __restrict__ pwb,   // [C][C] bf16 (o-major)
    const float* __restrict__ proj_b,
    const float* __restrict__ x,
    float* __restrict__ out)
{
    __shared__ __align__(16) unsigned short smem[17408];  // 34,816 B
    // main loop: per-wave P tile [32 n][72 l] shorts at smem + wave*2304
    // epilogue:  o_lds [128][136] shorts (aliases; barrier-guarded)

    const int b = blockIdx.y;
    const int n0 = blockIdx.x * 128;
    const int tid = threadIdx.x;
    const int wave = tid >> 6;
    const int lane = tid & 63;
    const int lrow = lane & 31;
    const int hi = lane >> 5;

    // Q A-fragments: row = lane&31, k = 8*hi + j, 8 chunks of K=16
    sv8 qa[8];
    {
        const unsigned short* qrow =
            qb + ((size_t)b * kHW + n0 + wave * 32 + lrow) * kC + hi * 8;
#pragma unroll
        for (int kc = 0; kc < 8; kc++)
            qa[kc] = *(const sv8*)(qrow + kc * 16);
    }

    f32x16 oacc[4];
#pragma unroll
    for (int ct = 0; ct < 4; ct++)
#pragma unroll
        for (int r = 0; r < 16; r++) oacc[ct][r] = 0.f;
    float rsum[16];
#pragma unroll
    for (int r = 0; r < 16; r++) rsum[r] = 0.f;

    unsigned short* myp = smem + wave * 2304;   // [32][72]
    const unsigned short* kvB  = kvb  + (size_t)b * kL * kC;
    const unsigned short* kvtB = kvtb + (size_t)b * kC * kL;

    for (int l0 = 0; l0 < kL; l0 += 64) {
        // ---- QK^T: S[n][l], 2 l-subtiles of 32; B straight from global ----
#pragma unroll
        for (int ls = 0; ls < 2; ls++) {
            f32x16 s;
#pragma unroll
            for (int r = 0; r < 16; r++) s[r] = 0.f;
            const unsigned short* brow = kvB + (size_t)(l0 + ls * 32 + lrow) * kC + hi * 8;
            __builtin_amdgcn_s_setprio(1);
#pragma unroll
            for (int kc = 0; kc < 8; kc++)
                s = __builtin_amdgcn_mfma_f32_32x32x16_bf16(
                        qa[kc], *(const sv8*)(brow + kc * 16), s, 0, 0, 0);
            __builtin_amdgcn_s_setprio(0);
            // exp (max-free: |logit| << 1), rowsum, P -> per-wave LDS (bf16)
#pragma unroll
            for (int r = 0; r < 16; r++) {
                float p = __expf(s[r]);
                rsum[r] += p;
                int n = (r & 3) + 8 * (r >> 2) + 4 * hi;
                myp[n * 72 + ls * 32 + lrow] = f2bf(p);
            }
        }
        // ---- PV: A = P (per-wave LDS, lgkm-only dep), B from global kvT ----
        sv8 pa[4];
#pragma unroll
        for (int kk = 0; kk < 4; kk++)
            pa[kk] = *(const sv8*)(myp + lrow * 72 + kk * 16 + hi * 8);
        __builtin_amdgcn_s_setprio(1);
#pragma unroll
        for (int ct = 0; ct < 4; ct++) {
            const unsigned short* brow = kvtB + (size_t)(ct * 32 + lrow) * kL + l0 + hi * 8;
#pragma unroll
            for (int kk = 0; kk < 4; kk++)
                oacc[ct] = __builtin_amdgcn_mfma_f32_32x32x16_bf16(
                               pa[kk], *(const sv8*)(brow + kk * 16), oacc[ct], 0, 0, 0);
        }
        __builtin_amdgcn_s_setprio(0);
    }

    // softmax denominators: reduce across the 32 l-columns
#pragma unroll
    for (int r = 0; r < 16; r++) {
        float v = rsum[r];
        v += __shfl_xor(v, 1, 64);
        v += __shfl_xor(v, 2, 64);
        v += __shfl_xor(v, 4, 64);
        v += __shfl_xor(v, 8, 64);
        v += __shfl_xor(v, 16, 64);
        rsum[r] = 1.f / v;
    }

    unsigned short* o_lds = smem;              // [128][136], aliases P pool
    __syncthreads();                           // all waves done with P
    // normalized O -> o_lds bf16 [128 n][136 c]  (per-wave row-disjoint)
#pragma unroll
    for (int ct = 0; ct < 4; ct++)
#pragma unroll
        for (int r = 0; r < 16; r++) {
            int n = wave * 32 + (r & 3) + 8 * (r >> 2) + 4 * hi;
            o_lds[n * 136 + ct * 32 + lrow] = f2bf(oacc[ct][r] * rsum[r]);
        }
    // proj: D[n][o] = O[n][c] * pw[o][c]
    sv8 oa[8];
    {
        const unsigned short* orow = o_lds + (wave * 32 + lrow) * 136 + hi * 8;
#pragma unroll
        for (int kc = 0; kc < 8; kc++) oa[kc] = *(const sv8*)(orow + kc * 16);
    }
    f32x16 dacc[4];
#pragma unroll
    for (int ot = 0; ot < 4; ot++)
#pragma unroll
        for (int r = 0; r < 16; r++) dacc[ot][r] = 0.f;
#pragma unroll
    for (int ot = 0; ot < 4; ot++) {
        const unsigned short* brow = pwb + (ot * 32 + lrow) * kC + hi * 8;
#pragma unroll
        for (int kc = 0; kc < 8; kc++)
            dacc[ot] = __builtin_amdgcn_mfma_f32_32x32x16_bf16(
                           oa[kc], *(const sv8*)(brow + kc * 16), dacc[ot], 0, 0, 0);
    }
    // D -> o_lds bf16 [128 n][136 o] (own rows only; reads already in regs)
#pragma unroll
    for (int ot = 0; ot < 4; ot++)
#pragma unroll
        for (int r = 0; r < 16; r++) {
            int n = wave * 32 + (r & 3) + 8 * (r >> 2) + 4 * hi;
            o_lds[n * 136 + ot * 32 + lrow] = f2bf(dacc[ot][r]);
        }
    __syncthreads();
    // epilogue: out[b][o][n0+n] = D[n][o] + proj_b[o] + x  (coalesced)
#pragma unroll 4
    for (int it = 0; it < 64; it++) {
        int idx = it * 256 + tid;
        int o = idx >> 7, n = idx & 127;
        size_t gi = ((size_t)b * kC + o) * kHW + n0 + n;
        out[gi] = bf2f(o_lds[n * 136 + o]) + proj_b[o] + x[gi];
    }
}

extern "C" void kernel_launch(void* const* d_in, const int* in_sizes, int n_in,
                              void* d_out, int out_size, void* d_ws, size_t ws_size,
                              hipStream_t stream) {
    const float* x      = (const float*)d_in[0];
    const float* nd     = (const float*)d_in[1];
    const float* gamma  = (const float*)d_in[2];
    const float* beta   = (const float*)d_in[3];
    const float* q_w    = (const float*)d_in[4];
    const float* q_b    = (const float*)d_in[5];
    const float* nd_w   = (const float*)d_in[6];
    const float* nd_b   = (const float*)d_in[7];
    const float* proj_w = (const float*)d_in[8];
    const float* proj_b = (const float*)d_in[9];
    float* out = (float*)d_out;

    float* stats          = (float*)d_ws;                  // 1024 f32
    unsigned short* pwb   = (unsigned short*)(stats + 1024);       // 16384
    unsigned short* kv_bf = pwb + 16384;                   // 1,048,576
    unsigned short* kvT_bf = kv_bf + (size_t)kB * kL * kC; // 1,048,576
    unsigned short* q_bf  = kvT_bf + (size_t)kB * kL * kC; // 8,388,608

    gn_stats_k<<<dim3(kB * kG), dim3(256), 0, stream>>>(x, stats);
    prep_k<<<dim3(16), dim3(256), 0, stream>>>(proj_w, pwb);
    kv_k<<<dim3(kL / 8, kB), dim3(256), 0, stream>>>(nd, nd_w, nd_b, kv_bf, kvT_bf);
    qproj_k<<<dim3(kHW / 128, kB), dim3(256), 0, stream>>>(x, stats, gamma, beta, q_w, q_b, q_bf);
    attn_k<<<dim3(kHW / 128, kB), dim3(256), 0, stream>>>(q_bf, kv_bf, kvT_bf, pwb,
                                                          proj_b, x, out);
}

// Round 6
// 109.532 us; speedup vs baseline: 1.9172x; 1.2644x over previous
//
#include <hip/hip_runtime.h>
#include <math.h>

constexpr int kB = 16, kC = 128, kHW = 4096, kL = 512, kND = 256, kG = 32;
constexpr float kEps = 1e-6f;
constexpr float kScale = 0.08838834764831845f;  // 128^-0.5

typedef short sv8 __attribute__((ext_vector_type(8)));
typedef int   iv4 __attribute__((ext_vector_type(4)));
typedef float f32x16 __attribute__((ext_vector_type(16)));

static __device__ __forceinline__ unsigned short f2bf(float f) {
    unsigned int u = __builtin_bit_cast(unsigned int, f);
    u += 0x7fffu + ((u >> 16) & 1u);
    return (unsigned short)(u >> 16);
}
static __device__ __forceinline__ float bf2f(unsigned short s) {
    unsigned int u = ((unsigned int)s) << 16;
    return __builtin_bit_cast(float, u);
}
static __device__ __forceinline__ unsigned int pack2(float a, float b) {
    return (unsigned int)f2bf(a) | ((unsigned int)f2bf(b) << 16);
}

// ---------------- Kernel 1: GroupNorm statistics ----------------
__global__ __launch_bounds__(256) void gn_stats_k(const float* __restrict__ x,
                                                  float* __restrict__ stats) {
    int bg = blockIdx.x;
    const float4* p4 = (const float4*)(x + (size_t)bg * 4 * kHW);
    int tid = threadIdx.x;
    float s = 0.f, ss = 0.f;
    for (int i = tid; i < 4096; i += 256) {
        float4 v = p4[i];
        s  += (v.x + v.y) + (v.z + v.w);
        ss += (v.x * v.x + v.y * v.y) + (v.z * v.z + v.w * v.w);
    }
#pragma unroll
    for (int off = 1; off < 64; off <<= 1) {
        s  += __shfl_xor(s, off, 64);
        ss += __shfl_xor(ss, off, 64);
    }
    __shared__ float red[8];
    int wid = tid >> 6;
    if ((tid & 63) == 0) { red[wid] = s; red[wid + 4] = ss; }
    __syncthreads();
    if (tid == 0) {
        float S  = (red[0] + red[1]) + (red[2] + red[3]);
        float SS = (red[4] + red[5]) + (red[6] + red[7]);
        float mean = S * (1.f / 16384.f);
        float var  = SS * (1.f / 16384.f) - mean * mean;
        stats[bg * 2]     = mean;
        stats[bg * 2 + 1] = rsqrtf(var + kEps);
    }
}

// ---------------- Kernel 1b: proj_w -> bf16 ----------------
__global__ __launch_bounds__(256) void prep_k(const float* __restrict__ w,
                                              unsigned short* __restrict__ wb) {
    int i = (blockIdx.x * 256 + threadIdx.x) * 4;
    float4 v = *(const float4*)(w + i);
    wb[i + 0] = f2bf(v.x); wb[i + 1] = f2bf(v.y);
    wb[i + 2] = f2bf(v.z); wb[i + 3] = f2bf(v.w);
}

// ---------------- Kernel 2: kv = silu(nd) @ nd_w^T + nd_b (bf16 + bf16^T) ----
__global__ __launch_bounds__(256) void kv_k(const float* __restrict__ nd,
                                            const float* __restrict__ nd_w,
                                            const float* __restrict__ nd_b,
                                            unsigned short* __restrict__ kv_bf,
                                            unsigned short* __restrict__ kvT_bf) {
    __shared__ float s_lds[8][256];
    __shared__ float w_lds[128][68];
    __shared__ float t_lds[8][129];
    int b = blockIdx.y;
    int l0 = blockIdx.x * 8;
    int tid = threadIdx.x;
    const float4* ndp = (const float4*)(nd + ((size_t)b * kL + l0) * kND);
#pragma unroll
    for (int r = 0; r < 2; r++) {
        int idx = tid + r * 256;
        int row = idx >> 6;
        int c4 = idx & 63;
        float4 v = ndp[row * 64 + c4];
        v.x = v.x / (1.f + __expf(-v.x));
        v.y = v.y / (1.f + __expf(-v.y));
        v.z = v.z / (1.f + __expf(-v.z));
        v.w = v.w / (1.f + __expf(-v.w));
        *(float4*)&s_lds[row][c4 * 4] = v;
    }
    float acc[4] = {0.f, 0.f, 0.f, 0.f};
    int lr = tid >> 5;
    int oq = tid & 31;
    for (int d0 = 0; d0 < kND; d0 += 64) {
        __syncthreads();
#pragma unroll
        for (int r = 0; r < 8; r++) {
            int idx = tid + r * 256;
            int row = idx >> 4;
            int c4 = idx & 15;
            float4 v = ((const float4*)(nd_w + (size_t)row * kND + d0))[c4];
            *(float4*)&w_lds[row][c4 * 4] = v;
        }
        __syncthreads();
        for (int dd = 0; dd < 64; dd += 4) {
            float4 sv = *(const float4*)&s_lds[lr][d0 + dd];
#pragma unroll
            for (int j = 0; j < 4; j++) {
                float4 wv = *(const float4*)&w_lds[oq + 32 * j][dd];
                acc[j] += sv.x * wv.x + sv.y * wv.y + sv.z * wv.z + sv.w * wv.w;
            }
        }
    }
#pragma unroll
    for (int j = 0; j < 4; j++) {
        int o = oq + 32 * j;
        float vout = acc[j] + nd_b[o];
        kv_bf[((size_t)b * kL + l0 + lr) * kC + o] = f2bf(vout);
        t_lds[lr][o] = vout;
    }
    __syncthreads();
    {
        int o = tid >> 1, lh = (tid & 1) * 4;
        unsigned long long pk = 0;
#pragma unroll
        for (int i = 0; i < 4; i++)
            pk |= (unsigned long long)f2bf(t_lds[lh + i][o]) << (16 * i);
        *(unsigned long long*)(kvT_bf + ((size_t)b * kC + o) * kL + l0 + lh) = pk;
    }
}

// ---------------- Kernel 3: q = (GN(x))^T @ q_w^T + q_b  (bf16 MFMA) -------
__global__ __launch_bounds__(256) void qproj_k(const float* __restrict__ x,
                                               const float* __restrict__ stats,
                                               const float* __restrict__ gamma,
                                               const float* __restrict__ beta,
                                               const float* __restrict__ q_w,
                                               const float* __restrict__ q_b,
                                               unsigned short* __restrict__ q_bf) {
    __shared__ __align__(16) unsigned short smem[17408];  // [128][136] bf16
    __shared__ float gab[256];                            // ga[128], be[128]
    const int b = blockIdx.y;
    const int n0 = blockIdx.x * 128;
    const int tid = threadIdx.x;
    const int wave = tid >> 6, lane = tid & 63;
    const int lrow = lane & 31, hi = lane >> 5;

    if (tid < 128) {
        float mean = stats[(b * kG + (tid >> 2)) * 2];
        float rstd = stats[(b * kG + (tid >> 2)) * 2 + 1];
        float ga = gamma[tid] * rstd;
        gab[tid] = ga;
        gab[128 + tid] = beta[tid] - mean * ga;
    }
    // stage q_w as bf16 [o][c], padded stride 136
#pragma unroll
    for (int r = 0; r < 16; r++) {
        int idx = tid + r * 256;            // 4096 float4 = 128x32
        int row = idx >> 5, c4 = idx & 31;
        float4 v = ((const float4*)q_w)[idx];
        unsigned int lo = (unsigned int)f2bf(v.x) | ((unsigned int)f2bf(v.y) << 16);
        unsigned int h2 = (unsigned int)f2bf(v.z) | ((unsigned int)f2bf(v.w) << 16);
        *(uint2*)&smem[row * 136 + c4 * 4] = make_uint2(lo, h2);
    }
    __syncthreads();

    // A fragments: hn[n][c] with GN fused, straight from global
    sv8 qa[8];
    {
        const float* xp = x + (size_t)b * kC * kHW + n0 + wave * 32 + lrow;
#pragma unroll
        for (int kc = 0; kc < 8; kc++) {
            int cb = kc * 16 + hi * 8;
            float4 g0 = *(const float4*)&gab[cb];
            float4 g1 = *(const float4*)&gab[cb + 4];
            float4 e0 = *(const float4*)&gab[128 + cb];
            float4 e1 = *(const float4*)&gab[128 + cb + 4];
            sv8 a;
            a[0] = (short)f2bf(xp[(size_t)(cb + 0) * kHW] * g0.x + e0.x);
            a[1] = (short)f2bf(xp[(size_t)(cb + 1) * kHW] * g0.y + e0.y);
            a[2] = (short)f2bf(xp[(size_t)(cb + 2) * kHW] * g0.z + e0.z);
            a[3] = (short)f2bf(xp[(size_t)(cb + 3) * kHW] * g0.w + e0.w);
            a[4] = (short)f2bf(xp[(size_t)(cb + 4) * kHW] * g1.x + e1.x);
            a[5] = (short)f2bf(xp[(size_t)(cb + 5) * kHW] * g1.y + e1.y);
            a[6] = (short)f2bf(xp[(size_t)(cb + 6) * kHW] * g1.z + e1.z);
            a[7] = (short)f2bf(xp[(size_t)(cb + 7) * kHW] * g1.w + e1.w);
            qa[kc] = a;
        }
    }

    f32x16 dacc[4];
#pragma unroll
    for (int ot = 0; ot < 4; ot++)
#pragma unroll
        for (int r = 0; r < 16; r++) dacc[ot][r] = 0.f;
#pragma unroll
    for (int ot = 0; ot < 4; ot++) {
        const unsigned short* brow = smem + (ot * 32 + lrow) * 136 + hi * 8;
#pragma unroll
        for (int kc = 0; kc < 8; kc++)
            dacc[ot] = __builtin_amdgcn_mfma_f32_32x32x16_bf16(
                           qa[kc], *(const sv8*)(brow + kc * 16), dacc[ot], 0, 0, 0);
    }
    __syncthreads();   // all B-reads done; reuse smem as q[n][o] transpose

#pragma unroll
    for (int ot = 0; ot < 4; ot++) {
        int o = ot * 32 + lrow;
        float qb = q_b[o];
#pragma unroll
        for (int r = 0; r < 16; r++) {
            int n_loc = wave * 32 + (r & 3) + 8 * (r >> 2) + 4 * hi;
            smem[n_loc * 136 + o] = f2bf((dacc[ot][r] + qb) * kScale);
        }
    }
    __syncthreads();
#pragma unroll
    for (int r = 0; r < 8; r++) {
        int idx = tid + r * 256;            // 2048 uint4 = 128 rows x 16
        int n = idx >> 4, ch = idx & 15;
        *(uint4*)(q_bf + ((size_t)b * kHW + n0 + n) * kC + ch * 8) =
            *(const uint4*)&smem[n * 136 + ch * 8];
    }
}

// ---------------- Kernel 4: MFMA attention + proj + residual ----------------
// Block: 128 Q-rows x 1 batch, 4 waves x 32 rows. Swapped QK^T (mfma(K,Q)):
// P lives in registers (no LDS round-trip); PV A-fragments assembled with
// 8 shfl_xor(32)/tile. kv/kvT tiles double-buffered in XOR-swizzled LDS,
// staged via reg-prefetch issued before compute, committed after (1 barrier
// per tile). LDS = 65 KB -> 2 blocks/CU; VGPR cap 256 (no spill).
__global__ __launch_bounds__(256, 2) void attn_k(
    const unsigned short* __restrict__ qb,    // [B][HW][C] bf16, pre-scaled
    const unsigned short* __restrict__ kvb,   // [B][L][C] bf16
    const unsigned short* __restrict__ kvtb,  // [B][C][L] bf16
    const unsigned short* __restrict__ pwb,   // [C][C] bf16 (o-major)
    const float* __restrict__ proj_b,
    const float* __restrict__ x,
    float* __restrict__ out)
{
    __shared__ __align__(16) char smem[66560];
    // kvA[2]: [0,16384),[16384,32768)   : [64 l][128 c] bf16, chunk16 ^= (l&7)
    // kvT[2]: [32768,49152),[49152,65536): [128 c][64 l] bf16, chunk16 ^= (c&7)
    // rs    : [65536,66048): 4 waves x 32 f32 (1/rowsum)
    // epilogue o_lds: ushort [128][136] at 0 (aliases; barrier-guarded)

    const int b = blockIdx.y;
    const int n0 = blockIdx.x * 128;
    const int tid = threadIdx.x;
    const int wave = tid >> 6;
    const int lane = tid & 63;
    const int lrow = lane & 31;
    const int hi = lane >> 5;
    const int swz = (lrow & 7) << 4;

    // Q fragments (serve as the B-operand of the swapped QK^T: same lane map)
    sv8 qa[8];
    {
        const unsigned short* qrow =
            qb + ((size_t)b * kHW + n0 + wave * 32 + lrow) * kC + hi * 8;
#pragma unroll
        for (int kc = 0; kc < 8; kc++)
            qa[kc] = *(const sv8*)(qrow + kc * 16);
    }

    f32x16 oacc[4];
#pragma unroll
    for (int ct = 0; ct < 4; ct++)
#pragma unroll
        for (int r = 0; r < 16; r++) oacc[ct][r] = 0.f;
    float rsumv = 0.f;

    uint4 pf[8];
    const uint4* gkv  = (const uint4*)(kvb  + (size_t)b * kL * kC);
    const uint4* gkvt = (const uint4*)(kvtb + (size_t)b * kC * kL);

    auto issue = [&](int t) {
        int l0 = t << 6;
#pragma unroll
        for (int r = 0; r < 4; r++) {
            int idx = tid + r * 256;                    // 1024 uint4 = 64x16
            pf[r] = gkv[(size_t)(l0 + (idx >> 4)) * 16 + (idx & 15)];
        }
#pragma unroll
        for (int r = 0; r < 4; r++) {
            int idx = tid + r * 256;                    // 1024 uint4 = 128x8
            pf[4 + r] = gkvt[(size_t)(idx >> 3) * 64 + (l0 >> 3) + (idx & 7)];
        }
    };
    auto commit = [&](char* bA, char* bT) {
#pragma unroll
        for (int r = 0; r < 4; r++) {
            int idx = tid + r * 256;
            int l = idx >> 4, ch = idx & 15;
            *(uint4*)(bA + l * 256 + ((ch ^ (l & 7)) * 16)) = pf[r];
        }
#pragma unroll
        for (int r = 0; r < 4; r++) {
            int idx = tid + r * 256;
            int c = idx >> 3, ch = idx & 7;
            *(uint4*)(bT + c * 128 + ((ch ^ (c & 7)) * 16)) = pf[4 + r];
        }
    };

    issue(0);
    commit(smem, smem + 32768);
    __syncthreads();

    for (int t = 0; t < 8; t++) {
        char* bufA = smem + (t & 1) * 16384;
        char* bufT = smem + 32768 + (t & 1) * 16384;
        if (t < 7) issue(t + 1);                   // loads in flight over compute

        // ---- swapped QK^T: S[l][n] = mfma(A=kv, B=q); exp in registers ----
        unsigned int pka[2][4], pkb[2][4];
#pragma unroll
        for (int ls = 0; ls < 2; ls++) {
            f32x16 s;
#pragma unroll
            for (int r = 0; r < 16; r++) s[r] = 0.f;
            const char* arow = bufA + (ls * 32 + lrow) * 256;
            __builtin_amdgcn_s_setprio(1);
#pragma unroll
            for (int kc = 0; kc < 8; kc++)
                s = __builtin_amdgcn_mfma_f32_32x32x16_bf16(
                        *(const sv8*)(arow + ((kc * 32 + hi * 16) ^ swz)),
                        qa[kc], s, 0, 0, 0);
            __builtin_amdgcn_s_setprio(0);
            float p[16];
#pragma unroll
            for (int r = 0; r < 16; r++) {
                p[r] = __expf(s[r]);              // max-free: |logit| << 1
                rsumv += p[r];
            }
#pragma unroll
            for (int g = 0; g < 4; g++) {
                pka[ls][g] = pack2(p[4 * g + 0], p[4 * g + 1]);
                pkb[ls][g] = pack2(p[4 * g + 2], p[4 * g + 3]);
            }
        }
        // ---- assemble PV A-fragments: lane n holds P[n][l], l=kk*16+hi*8+j.
        // Own half supplies 4 elems, partner lane (^32) the other 4.
        sv8 pv[4];
#pragma unroll
        for (int kk = 0; kk < 4; kk++) {
            int ls = kk >> 1;
            unsigned int a_lo = pka[ls][(kk & 1) * 2], a_hi = pka[ls][(kk & 1) * 2 + 1];
            unsigned int b_lo = pkb[ls][(kk & 1) * 2], b_hi = pkb[ls][(kk & 1) * 2 + 1];
            unsigned int own_a = hi ? a_hi : a_lo;
            unsigned int own_b = hi ? b_hi : b_lo;
            unsigned int rcv_a = (unsigned int)__shfl_xor((int)(hi ? a_lo : a_hi), 32, 64);
            unsigned int rcv_b = (unsigned int)__shfl_xor((int)(hi ? b_lo : b_hi), 32, 64);
            iv4 w;
            w[0] = (int)(hi ? rcv_a : own_a);
            w[1] = (int)(hi ? rcv_b : own_b);
            w[2] = (int)(hi ? own_a : rcv_a);
            w[3] = (int)(hi ? own_b : rcv_b);
            pv[kk] = __builtin_bit_cast(sv8, w);
        }
        // ---- PV: O[n][c] += P[n][l] * kv[l][c]; B from swizzled kvT ----
        __builtin_amdgcn_s_setprio(1);
#pragma unroll
        for (int ct = 0; ct < 4; ct++) {
            const char* rowp = bufT + (ct * 32 + lrow) * 128;
#pragma unroll
            for (int kk = 0; kk < 4; kk++)
                oacc[ct] = __builtin_amdgcn_mfma_f32_32x32x16_bf16(
                               pv[kk],
                               *(const sv8*)(rowp + ((kk * 32 + hi * 16) ^ swz)),
                               oacc[ct], 0, 0, 0);
        }
        __builtin_amdgcn_s_setprio(0);

        if (t < 7) commit(smem + ((t + 1) & 1) * 16384,
                          smem + 32768 + ((t + 1) & 1) * 16384);
        __syncthreads();
    }

    // ---- softmax denominators: lane n has column-sum over its 32 l's ----
    float total = rsumv + __shfl_xor(rsumv, 32, 64);
    float* rs = (float*)(smem + 65536) + wave * 32;
    rs[lrow] = 1.0f / total;                 // both halves write same value
    float rinv[16];
#pragma unroll
    for (int r = 0; r < 16; r++)
        rinv[r] = rs[(r & 3) + 8 * (r >> 2) + 4 * hi];

    unsigned short* o_lds = (unsigned short*)smem;   // [128][136]
    __syncthreads();
    // normalized O -> o_lds bf16 [128 n][136 c]  (per-wave row-disjoint)
#pragma unroll
    for (int ct = 0; ct < 4; ct++)
#pragma unroll
        for (int r = 0; r < 16; r++) {
            int n = wave * 32 + (r & 3) + 8 * (r >> 2) + 4 * hi;
            o_lds[n * 136 + ct * 32 + lrow] = f2bf(oacc[ct][r] * rinv[r]);
        }
    // proj: D[n][o] = O[n][c] * pw[o][c]
    sv8 oa[8];
    {
        const unsigned short* orow = o_lds + (wave * 32 + lrow) * 136 + hi * 8;
#pragma unroll
        for (int kc = 0; kc < 8; kc++) oa[kc] = *(const sv8*)(orow + kc * 16);
    }
    f32x16 dacc[4];
#pragma unroll
    for (int ot = 0; ot < 4; ot++)
#pragma unroll
        for (int r = 0; r < 16; r++) dacc[ot][r] = 0.f;
#pragma unroll
    for (int ot = 0; ot < 4; ot++) {
        const unsigned short* brow = pwb + (ot * 32 + lrow) * kC + hi * 8;
#pragma unroll
        for (int kc = 0; kc < 8; kc++)
            dacc[ot] = __builtin_amdgcn_mfma_f32_32x32x16_bf16(
                           oa[kc], *(const sv8*)(brow + kc * 16), dacc[ot], 0, 0, 0);
    }
    // D -> o_lds bf16 [128 n][136 o] (own rows only; reads already in regs)
#pragma unroll
    for (int ot = 0; ot < 4; ot++)
#pragma unroll
        for (int r = 0; r < 16; r++) {
            int n = wave * 32 + (r & 3) + 8 * (r >> 2) + 4 * hi;
            o_lds[n * 136 + ot * 32 + lrow] = f2bf(dacc[ot][r]);
        }
    __syncthreads();
    // epilogue: out[b][o][n0+n] = D[n][o] + proj_b[o] + x  (coalesced)
#pragma unroll 4
    for (int it = 0; it < 64; it++) {
        int idx = it * 256 + tid;
        int o = idx >> 7, n = idx & 127;
        size_t gi = ((size_t)b * kC + o) * kHW + n0 + n;
        out[gi] = bf2f(o_lds[n * 136 + o]) + proj_b[o] + x[gi];
    }
}

extern "C" void kernel_launch(void* const* d_in, const int* in_sizes, int n_in,
                              void* d_out, int out_size, void* d_ws, size_t ws_size,
                              hipStream_t stream) {
    const float* x      = (const float*)d_in[0];
    const float* nd     = (const float*)d_in[1];
    const float* gamma  = (const float*)d_in[2];
    const float* beta   = (const float*)d_in[3];
    const float* q_w    = (const float*)d_in[4];
    const float* q_b    = (const float*)d_in[5];
    const float* nd_w   = (const float*)d_in[6];
    const float* nd_b   = (const float*)d_in[7];
    const float* proj_w = (const float*)d_in[8];
    const float* proj_b = (const float*)d_in[9];
    float* out = (float*)d_out;

    float* stats          = (float*)d_ws;                  // 1024 f32
    unsigned short* pwb   = (unsigned short*)(stats + 1024);       // 16384
    unsigned short* kv_bf = pwb + 16384;                   // 1,048,576
    unsigned short* kvT_bf = kv_bf + (size_t)kB * kL * kC; // 1,048,576
    unsigned short* q_bf  = kvT_bf + (size_t)kB * kL * kC; // 8,388,608

    gn_stats_k<<<dim3(kB * kG), dim3(256), 0, stream>>>(x, stats);
    prep_k<<<dim3(16), dim3(256), 0, stream>>>(proj_w, pwb);
    kv_k<<<dim3(kL / 8, kB), dim3(256), 0, stream>>>(nd, nd_w, nd_b, kv_bf, kvT_bf);
    qproj_k<<<dim3(kHW / 128, kB), dim3(256), 0, stream>>>(x, stats, gamma, beta, q_w, q_b, q_bf);
    attn_k<<<dim3(kHW / 128, kB), dim3(256), 0, stream>>>(q_bf, kv_bf, kvT_bf, pwb,
                                                          proj_b, x, out);
}

// Round 7
// 98.893 us; speedup vs baseline: 2.1235x; 1.1076x over previous
//
#include <hip/hip_runtime.h>
#include <math.h>

constexpr int kB = 16, kC = 128, kHW = 4096, kL = 512, kND = 256, kG = 32;
constexpr float kEps = 1e-6f;
constexpr float kScale = 0.08838834764831845f;  // 128^-0.5

typedef short sv8 __attribute__((ext_vector_type(8)));
typedef int   iv4 __attribute__((ext_vector_type(4)));
typedef float f32x16 __attribute__((ext_vector_type(16)));

static __device__ __forceinline__ unsigned short f2bf(float f) {
    unsigned int u = __builtin_bit_cast(unsigned int, f);
    u += 0x7fffu + ((u >> 16) & 1u);
    return (unsigned short)(u >> 16);
}
static __device__ __forceinline__ float bf2f(unsigned short s) {
    unsigned int u = ((unsigned int)s) << 16;
    return __builtin_bit_cast(float, u);
}
static __device__ __forceinline__ unsigned int pack2(float a, float b) {
    return (unsigned int)f2bf(a) | ((unsigned int)f2bf(b) << 16);
}

// ---------------- Kernel 1: GroupNorm statistics ----------------
__global__ __launch_bounds__(256) void gn_stats_k(const float* __restrict__ x,
                                                  float* __restrict__ stats) {
    int bg = blockIdx.x;
    const float4* p4 = (const float4*)(x + (size_t)bg * 4 * kHW);
    int tid = threadIdx.x;
    float s = 0.f, ss = 0.f;
    for (int i = tid; i < 4096; i += 256) {
        float4 v = p4[i];
        s  += (v.x + v.y) + (v.z + v.w);
        ss += (v.x * v.x + v.y * v.y) + (v.z * v.z + v.w * v.w);
    }
#pragma unroll
    for (int off = 1; off < 64; off <<= 1) {
        s  += __shfl_xor(s, off, 64);
        ss += __shfl_xor(ss, off, 64);
    }
    __shared__ float red[8];
    int wid = tid >> 6;
    if ((tid & 63) == 0) { red[wid] = s; red[wid + 4] = ss; }
    __syncthreads();
    if (tid == 0) {
        float S  = (red[0] + red[1]) + (red[2] + red[3]);
        float SS = (red[4] + red[5]) + (red[6] + red[7]);
        float mean = S * (1.f / 16384.f);
        float var  = SS * (1.f / 16384.f) - mean * mean;
        stats[bg * 2]     = mean;
        stats[bg * 2 + 1] = rsqrtf(var + kEps);
    }
}

// ---------------- Kernel 1b: proj_w -> bf16 ----------------
__global__ __launch_bounds__(256) void prep_k(const float* __restrict__ w,
                                              unsigned short* __restrict__ wb) {
    int i = (blockIdx.x * 256 + threadIdx.x) * 4;
    float4 v = *(const float4*)(w + i);
    wb[i + 0] = f2bf(v.x); wb[i + 1] = f2bf(v.y);
    wb[i + 2] = f2bf(v.z); wb[i + 3] = f2bf(v.w);
}

// ---------------- Kernel 2: kv = silu(nd) @ nd_w^T + nd_b (bf16 + bf16^T) ----
__global__ __launch_bounds__(256) void kv_k(const float* __restrict__ nd,
                                            const float* __restrict__ nd_w,
                                            const float* __restrict__ nd_b,
                                            unsigned short* __restrict__ kv_bf,
                                            unsigned short* __restrict__ kvT_bf) {
    __shared__ float s_lds[8][256];
    __shared__ float w_lds[128][68];
    __shared__ float t_lds[8][129];
    int b = blockIdx.y;
    int l0 = blockIdx.x * 8;
    int tid = threadIdx.x;
    const float4* ndp = (const float4*)(nd + ((size_t)b * kL + l0) * kND);
#pragma unroll
    for (int r = 0; r < 2; r++) {
        int idx = tid + r * 256;
        int row = idx >> 6;
        int c4 = idx & 63;
        float4 v = ndp[row * 64 + c4];
        v.x = v.x / (1.f + __expf(-v.x));
        v.y = v.y / (1.f + __expf(-v.y));
        v.z = v.z / (1.f + __expf(-v.z));
        v.w = v.w / (1.f + __expf(-v.w));
        *(float4*)&s_lds[row][c4 * 4] = v;
    }
    float acc[4] = {0.f, 0.f, 0.f, 0.f};
    int lr = tid >> 5;
    int oq = tid & 31;
    for (int d0 = 0; d0 < kND; d0 += 64) {
        __syncthreads();
#pragma unroll
        for (int r = 0; r < 8; r++) {
            int idx = tid + r * 256;
            int row = idx >> 4;
            int c4 = idx & 15;
            float4 v = ((const float4*)(nd_w + (size_t)row * kND + d0))[c4];
            *(float4*)&w_lds[row][c4 * 4] = v;
        }
        __syncthreads();
        for (int dd = 0; dd < 64; dd += 4) {
            float4 sv = *(const float4*)&s_lds[lr][d0 + dd];
#pragma unroll
            for (int j = 0; j < 4; j++) {
                float4 wv = *(const float4*)&w_lds[oq + 32 * j][dd];
                acc[j] += sv.x * wv.x + sv.y * wv.y + sv.z * wv.z + sv.w * wv.w;
            }
        }
    }
#pragma unroll
    for (int j = 0; j < 4; j++) {
        int o = oq + 32 * j;
        float vout = acc[j] + nd_b[o];
        kv_bf[((size_t)b * kL + l0 + lr) * kC + o] = f2bf(vout);
        t_lds[lr][o] = vout;
    }
    __syncthreads();
    {
        int o = tid >> 1, lh = (tid & 1) * 4;
        unsigned long long pk = 0;
#pragma unroll
        for (int i = 0; i < 4; i++)
            pk |= (unsigned long long)f2bf(t_lds[lh + i][o]) << (16 * i);
        *(unsigned long long*)(kvT_bf + ((size_t)b * kC + o) * kL + l0 + lh) = pk;
    }
}

// ---------------- Kernel 3: q = (GN(x))^T @ q_w^T + q_b  (bf16 MFMA) -------
__global__ __launch_bounds__(256) void qproj_k(const float* __restrict__ x,
                                               const float* __restrict__ stats,
                                               const float* __restrict__ gamma,
                                               const float* __restrict__ beta,
                                               const float* __restrict__ q_w,
                                               const float* __restrict__ q_b,
                                               unsigned short* __restrict__ q_bf) {
    __shared__ __align__(16) unsigned short smem[17408];  // [128][136] bf16
    __shared__ float gab[256];                            // ga[128], be[128]
    const int b = blockIdx.y;
    const int n0 = blockIdx.x * 128;
    const int tid = threadIdx.x;
    const int wave = tid >> 6, lane = tid & 63;
    const int lrow = lane & 31, hi = lane >> 5;

    if (tid < 128) {
        float mean = stats[(b * kG + (tid >> 2)) * 2];
        float rstd = stats[(b * kG + (tid >> 2)) * 2 + 1];
        float ga = gamma[tid] * rstd;
        gab[tid] = ga;
        gab[128 + tid] = beta[tid] - mean * ga;
    }
    // stage q_w as bf16 [o][c], padded stride 136
#pragma unroll
    for (int r = 0; r < 16; r++) {
        int idx = tid + r * 256;            // 4096 float4 = 128x32
        int row = idx >> 5, c4 = idx & 31;
        float4 v = ((const float4*)q_w)[idx];
        unsigned int lo = (unsigned int)f2bf(v.x) | ((unsigned int)f2bf(v.y) << 16);
        unsigned int h2 = (unsigned int)f2bf(v.z) | ((unsigned int)f2bf(v.w) << 16);
        *(uint2*)&smem[row * 136 + c4 * 4] = make_uint2(lo, h2);
    }
    __syncthreads();

    // A fragments: hn[n][c] with GN fused, straight from global
    sv8 qa[8];
    {
        const float* xp = x + (size_t)b * kC * kHW + n0 + wave * 32 + lrow;
#pragma unroll
        for (int kc = 0; kc < 8; kc++) {
            int cb = kc * 16 + hi * 8;
            float4 g0 = *(const float4*)&gab[cb];
            float4 g1 = *(const float4*)&gab[cb + 4];
            float4 e0 = *(const float4*)&gab[128 + cb];
            float4 e1 = *(const float4*)&gab[128 + cb + 4];
            sv8 a;
            a[0] = (short)f2bf(xp[(size_t)(cb + 0) * kHW] * g0.x + e0.x);
            a[1] = (short)f2bf(xp[(size_t)(cb + 1) * kHW] * g0.y + e0.y);
            a[2] = (short)f2bf(xp[(size_t)(cb + 2) * kHW] * g0.z + e0.z);
            a[3] = (short)f2bf(xp[(size_t)(cb + 3) * kHW] * g0.w + e0.w);
            a[4] = (short)f2bf(xp[(size_t)(cb + 4) * kHW] * g1.x + e1.x);
            a[5] = (short)f2bf(xp[(size_t)(cb + 5) * kHW] * g1.y + e1.y);
            a[6] = (short)f2bf(xp[(size_t)(cb + 6) * kHW] * g1.z + e1.z);
            a[7] = (short)f2bf(xp[(size_t)(cb + 7) * kHW] * g1.w + e1.w);
            qa[kc] = a;
        }
    }

    f32x16 dacc[4];
#pragma unroll
    for (int ot = 0; ot < 4; ot++)
#pragma unroll
        for (int r = 0; r < 16; r++) dacc[ot][r] = 0.f;
#pragma unroll
    for (int ot = 0; ot < 4; ot++) {
        const unsigned short* brow = smem + (ot * 32 + lrow) * 136 + hi * 8;
#pragma unroll
        for (int kc = 0; kc < 8; kc++)
            dacc[ot] = __builtin_amdgcn_mfma_f32_32x32x16_bf16(
                           qa[kc], *(const sv8*)(brow + kc * 16), dacc[ot], 0, 0, 0);
    }
    __syncthreads();   // all B-reads done; reuse smem as q[n][o] transpose

#pragma unroll
    for (int ot = 0; ot < 4; ot++) {
        int o = ot * 32 + lrow;
        float qb = q_b[o];
#pragma unroll
        for (int r = 0; r < 16; r++) {
            int n_loc = wave * 32 + (r & 3) + 8 * (r >> 2) + 4 * hi;
            smem[n_loc * 136 + o] = f2bf((dacc[ot][r] + qb) * kScale);
        }
    }
    __syncthreads();
#pragma unroll
    for (int r = 0; r < 8; r++) {
        int idx = tid + r * 256;            // 2048 uint4 = 128 rows x 16
        int n = idx >> 4, ch = idx & 15;
        *(uint4*)(q_bf + ((size_t)b * kHW + n0 + n) * kC + ch * 8) =
            *(const uint4*)&smem[n * 136 + ch * 8];
    }
}

// ---------------- Kernel 4: MFMA attention + proj + residual ----------------
// Block: 128 Q-rows x 1 batch, 4 waves x 32 rows. Swapped QK^T (mfma(K,Q)):
// P stays in registers. kv/kvT double-buffered in XOR-swizzled LDS; prefetch
// code inlined (NO lambdas: lambda capture of pf[] made it address-escape ->
// scratch spill -> +105 MB HBM writes in round 6). kvA swizzle widened to
// 4 bits (2-way, free); kvT rows are 128 B so 3-bit is the max.
__global__ __launch_bounds__(256, 2) void attn_k(
    const unsigned short* __restrict__ qb,    // [B][HW][C] bf16, pre-scaled
    const unsigned short* __restrict__ kvb,   // [B][L][C] bf16
    const unsigned short* __restrict__ kvtb,  // [B][C][L] bf16
    const unsigned short* __restrict__ pwb,   // [C][C] bf16 (o-major)
    const float* __restrict__ proj_b,
    const float* __restrict__ x,
    float* __restrict__ out)
{
    __shared__ __align__(16) char smem[66560];
    // kvA[2]: [0,16384),[16384,32768)    : [64 l][128 c] bf16, ch16 ^= (l&15)
    // kvT[2]: [32768,49152),[49152,65536): [128 c][64 l] bf16, ch16 ^= (c&7)
    // rs    : [65536,66048): 4 waves x 32 f32 (1/rowsum)
    // epilogue o_lds: ushort [128][136] at 0 (aliases; barrier-guarded)

    const int b = blockIdx.y;
    const int n0 = blockIdx.x * 128;
    const int tid = threadIdx.x;
    const int wave = tid >> 6;
    const int lane = tid & 63;
    const int lrow = lane & 31;
    const int hi = lane >> 5;
    const int swzA = (lrow & 15) << 4;
    const int swzT = (lrow & 7) << 4;

    // Q fragments (serve as the B-operand of the swapped QK^T: same lane map)
    sv8 qa[8];
    {
        const unsigned short* qrow =
            qb + ((size_t)b * kHW + n0 + wave * 32 + lrow) * kC + hi * 8;
#pragma unroll
        for (int kc = 0; kc < 8; kc++)
            qa[kc] = *(const sv8*)(qrow + kc * 16);
    }

    f32x16 oacc[4];
#pragma unroll
    for (int ct = 0; ct < 4; ct++)
#pragma unroll
        for (int r = 0; r < 16; r++) oacc[ct][r] = 0.f;
    float rsumv = 0.f;

    const uint4* gkv  = (const uint4*)(kvb  + (size_t)b * kL * kC);
    const uint4* gkvt = (const uint4*)(kvtb + (size_t)b * kC * kL);
    uint4 pf[8];

    // ---- prologue: load + commit tile 0 (inline, no lambdas) ----
#pragma unroll
    for (int r = 0; r < 4; r++) {
        int idx = tid + r * 256;                    // 1024 uint4 = 64x16
        pf[r] = gkv[(size_t)(idx >> 4) * 16 + (idx & 15)];
    }
#pragma unroll
    for (int r = 0; r < 4; r++) {
        int idx = tid + r * 256;                    // 1024 uint4 = 128x8
        pf[4 + r] = gkvt[(size_t)(idx >> 3) * 64 + (idx & 7)];
    }
#pragma unroll
    for (int r = 0; r < 4; r++) {
        int idx = tid + r * 256;
        int l = idx >> 4, ch = idx & 15;
        *(uint4*)(smem + l * 256 + ((ch ^ (l & 15)) * 16)) = pf[r];
    }
#pragma unroll
    for (int r = 0; r < 4; r++) {
        int idx = tid + r * 256;
        int c = idx >> 3, ch = idx & 7;
        *(uint4*)(smem + 32768 + c * 128 + ((ch ^ (c & 7)) * 16)) = pf[4 + r];
    }
    __syncthreads();

    for (int t = 0; t < 8; t++) {
        const char* bufA = smem + (t & 1) * 16384;
        const char* bufT = smem + 32768 + (t & 1) * 16384;

        if (t < 7) {    // issue next tile's loads (stay in flight over compute)
            int l0 = (t + 1) << 6;
#pragma unroll
            for (int r = 0; r < 4; r++) {
                int idx = tid + r * 256;
                pf[r] = gkv[(size_t)(l0 + (idx >> 4)) * 16 + (idx & 15)];
            }
#pragma unroll
            for (int r = 0; r < 4; r++) {
                int idx = tid + r * 256;
                pf[4 + r] = gkvt[(size_t)(idx >> 3) * 64 + (l0 >> 3) + (idx & 7)];
            }
        }

        // ---- swapped QK^T: S[l][n] = mfma(A=kv, B=q); exp in registers ----
        unsigned int pka[2][4], pkb[2][4];
#pragma unroll
        for (int ls = 0; ls < 2; ls++) {
            f32x16 s;
#pragma unroll
            for (int r = 0; r < 16; r++) s[r] = 0.f;
            const char* arow = bufA + (ls * 32 + lrow) * 256;
            __builtin_amdgcn_s_setprio(1);
#pragma unroll
            for (int kc = 0; kc < 8; kc++)
                s = __builtin_amdgcn_mfma_f32_32x32x16_bf16(
                        *(const sv8*)(arow + ((kc * 32 + hi * 16) ^ swzA)),
                        qa[kc], s, 0, 0, 0);
            __builtin_amdgcn_s_setprio(0);
            float p[16];
#pragma unroll
            for (int r = 0; r < 16; r++) {
                p[r] = __expf(s[r]);              // max-free: |logit| << 1
                rsumv += p[r];
            }
#pragma unroll
            for (int g = 0; g < 4; g++) {
                pka[ls][g] = pack2(p[4 * g + 0], p[4 * g + 1]);
                pkb[ls][g] = pack2(p[4 * g + 2], p[4 * g + 3]);
            }
        }
        // ---- assemble PV A-fragments: lane n holds P[n][l], l=kk*16+hi*8+j.
        sv8 pv[4];
#pragma unroll
        for (int kk = 0; kk < 4; kk++) {
            int ls = kk >> 1;
            unsigned int a_lo = pka[ls][(kk & 1) * 2], a_hi = pka[ls][(kk & 1) * 2 + 1];
            unsigned int b_lo = pkb[ls][(kk & 1) * 2], b_hi = pkb[ls][(kk & 1) * 2 + 1];
            unsigned int own_a = hi ? a_hi : a_lo;
            unsigned int own_b = hi ? b_hi : b_lo;
            unsigned int rcv_a = (unsigned int)__shfl_xor((int)(hi ? a_lo : a_hi), 32, 64);
            unsigned int rcv_b = (unsigned int)__shfl_xor((int)(hi ? b_lo : b_hi), 32, 64);
            iv4 w;
            w[0] = (int)(hi ? rcv_a : own_a);
            w[1] = (int)(hi ? rcv_b : own_b);
            w[2] = (int)(hi ? own_a : rcv_a);
            w[3] = (int)(hi ? own_b : rcv_b);
            pv[kk] = __builtin_bit_cast(sv8, w);
        }
        // ---- PV: O[n][c] += P[n][l] * kv[l][c]; B from swizzled kvT ----
        __builtin_amdgcn_s_setprio(1);
#pragma unroll
        for (int ct = 0; ct < 4; ct++) {
            const char* rowp = bufT + (ct * 32 + lrow) * 128;
#pragma unroll
            for (int kk = 0; kk < 4; kk++)
                oacc[ct] = __builtin_amdgcn_mfma_f32_32x32x16_bf16(
                               pv[kk],
                               *(const sv8*)(rowp + ((kk * 32 + hi * 16) ^ swzT)),
                               oacc[ct], 0, 0, 0);
        }
        __builtin_amdgcn_s_setprio(0);

        if (t < 7) {    // commit next tile into the other buffer
            char* dA = smem + ((t + 1) & 1) * 16384;
            char* dT = smem + 32768 + ((t + 1) & 1) * 16384;
#pragma unroll
            for (int r = 0; r < 4; r++) {
                int idx = tid + r * 256;
                int l = idx >> 4, ch = idx & 15;
                *(uint4*)(dA + l * 256 + ((ch ^ (l & 15)) * 16)) = pf[r];
            }
#pragma unroll
            for (int r = 0; r < 4; r++) {
                int idx = tid + r * 256;
                int c = idx >> 3, ch = idx & 7;
                *(uint4*)(dT + c * 128 + ((ch ^ (c & 7)) * 16)) = pf[4 + r];
            }
        }
        __syncthreads();
    }

    // ---- softmax denominators: lane n has column-sum over its 32 l's ----
    float total = rsumv + __shfl_xor(rsumv, 32, 64);
    float* rs = (float*)(smem + 65536) + wave * 32;
    rs[lrow] = 1.0f / total;                 // both halves write same value
    float rinv[16];
#pragma unroll
    for (int r = 0; r < 16; r++)
        rinv[r] = rs[(r & 3) + 8 * (r >> 2) + 4 * hi];

    unsigned short* o_lds = (unsigned short*)smem;   // [128][136]
    __syncthreads();
    // normalized O -> o_lds bf16 [128 n][136 c]  (per-wave row-disjoint)
#pragma unroll
    for (int ct = 0; ct < 4; ct++)
#pragma unroll
        for (int r = 0; r < 16; r++) {
            int n = wave * 32 + (r & 3) + 8 * (r >> 2) + 4 * hi;
            o_lds[n * 136 + ct * 32 + lrow] = f2bf(oacc[ct][r] * rinv[r]);
        }
    // proj: D[n][o] = O[n][c] * pw[o][c]
    sv8 oa[8];
    {
        const unsigned short* orow = o_lds + (wave * 32 + lrow) * 136 + hi * 8;
#pragma unroll
        for (int kc = 0; kc < 8; kc++) oa[kc] = *(const sv8*)(orow + kc * 16);
    }
    f32x16 dacc[4];
#pragma unroll
    for (int ot = 0; ot < 4; ot++)
#pragma unroll
        for (int r = 0; r < 16; r++) dacc[ot][r] = 0.f;
#pragma unroll
    for (int ot = 0; ot < 4; ot++) {
        const unsigned short* brow = pwb + (ot * 32 + lrow) * kC + hi * 8;
#pragma unroll
        for (int kc = 0; kc < 8; kc++)
            dacc[ot] = __builtin_amdgcn_mfma_f32_32x32x16_bf16(
                           oa[kc], *(const sv8*)(brow + kc * 16), dacc[ot], 0, 0, 0);
    }
    // D -> o_lds bf16 [128 n][136 o] (own rows only; reads already in regs)
#pragma unroll
    for (int ot = 0; ot < 4; ot++)
#pragma unroll
        for (int r = 0; r < 16; r++) {
            int n = wave * 32 + (r & 3) + 8 * (r >> 2) + 4 * hi;
            o_lds[n * 136 + ot * 32 + lrow] = f2bf(dacc[ot][r]);
        }
    __syncthreads();
    // epilogue: out[b][o][n0+n] = D[n][o] + proj_b[o] + x  (coalesced)
#pragma unroll 4
    for (int it = 0; it < 64; it++) {
        int idx = it * 256 + tid;
        int o = idx >> 7, n = idx & 127;
        size_t gi = ((size_t)b * kC + o) * kHW + n0 + n;
        out[gi] = bf2f(o_lds[n * 136 + o]) + proj_b[o] + x[gi];
    }
}

extern "C" void kernel_launch(void* const* d_in, const int* in_sizes, int n_in,
                              void* d_out, int out_size, void* d_ws, size_t ws_size,
                              hipStream_t stream) {
    const float* x      = (const float*)d_in[0];
    const float* nd     = (const float*)d_in[1];
    const float* gamma  = (const float*)d_in[2];
    const float* beta   = (const float*)d_in[3];
    const float* q_w    = (const float*)d_in[4];
    const float* q_b    = (const float*)d_in[5];
    const float* nd_w   = (const float*)d_in[6];
    const float* nd_b   = (const float*)d_in[7];
    const float* proj_w = (const float*)d_in[8];
    const float* proj_b = (const float*)d_in[9];
    float* out = (float*)d_out;

    float* stats          = (float*)d_ws;                  // 1024 f32
    unsigned short* pwb   = (unsigned short*)(stats + 1024);       // 16384
    unsigned short* kv_bf = pwb + 16384;                   // 1,048,576
    unsigned short* kvT_bf = kv_bf + (size_t)kB * kL * kC; // 1,048,576
    unsigned short* q_bf  = kvT_bf + (size_t)kB * kL * kC; // 8,388,608

    gn_stats_k<<<dim3(kB * kG), dim3(256), 0, stream>>>(x, stats);
    prep_k<<<dim3(16), dim3(256), 0, stream>>>(proj_w, pwb);
    kv_k<<<dim3(kL / 8, kB), dim3(256), 0, stream>>>(nd, nd_w, nd_b, kv_bf, kvT_bf);
    qproj_k<<<dim3(kHW / 128, kB), dim3(256), 0, stream>>>(x, stats, gamma, beta, q_w, q_b, q_bf);
    attn_k<<<dim3(kHW / 128, kB), dim3(256), 0, stream>>>(q_bf, kv_bf, kvT_bf, pwb,
                                                          proj_b, x, out);
}

// Round 8
// 95.673 us; speedup vs baseline: 2.1950x; 1.0337x over previous
//
#include <hip/hip_runtime.h>
#include <math.h>

constexpr int kB = 16, kC = 128, kHW = 4096, kL = 512, kND = 256, kG = 32;
constexpr float kEps = 1e-6f;
constexpr float kScale = 0.08838834764831845f;  // 128^-0.5

typedef short sv8 __attribute__((ext_vector_type(8)));
typedef int   iv4 __attribute__((ext_vector_type(4)));
typedef float f32x16 __attribute__((ext_vector_type(16)));

static __device__ __forceinline__ unsigned short f2bf(float f) {
    unsigned int u = __builtin_bit_cast(unsigned int, f);
    u += 0x7fffu + ((u >> 16) & 1u);
    return (unsigned short)(u >> 16);
}
static __device__ __forceinline__ float bf2f(unsigned short s) {
    unsigned int u = ((unsigned int)s) << 16;
    return __builtin_bit_cast(float, u);
}
static __device__ __forceinline__ unsigned int pack2(float a, float b) {
    return (unsigned int)f2bf(a) | ((unsigned int)f2bf(b) << 16);
}

// Direct global->LDS async copy, 16 B/lane. LDS dest is wave-uniform base +
// lane*16 (linear); swizzle is applied by permuting the per-lane SOURCE.
#define GLOAD_LDS16(gp, lp)                                                     \
    __builtin_amdgcn_global_load_lds(                                           \
        (const __attribute__((address_space(1))) void*)(gp),                    \
        (__attribute__((address_space(3))) void*)(lp), 16, 0, 0)

// ---------------- Kernel 1: GroupNorm statistics ----------------
__global__ __launch_bounds__(256) void gn_stats_k(const float* __restrict__ x,
                                                  float* __restrict__ stats) {
    int bg = blockIdx.x;
    const float4* p4 = (const float4*)(x + (size_t)bg * 4 * kHW);
    int tid = threadIdx.x;
    float s = 0.f, ss = 0.f;
    for (int i = tid; i < 4096; i += 256) {
        float4 v = p4[i];
        s  += (v.x + v.y) + (v.z + v.w);
        ss += (v.x * v.x + v.y * v.y) + (v.z * v.z + v.w * v.w);
    }
#pragma unroll
    for (int off = 1; off < 64; off <<= 1) {
        s  += __shfl_xor(s, off, 64);
        ss += __shfl_xor(ss, off, 64);
    }
    __shared__ float red[8];
    int wid = tid >> 6;
    if ((tid & 63) == 0) { red[wid] = s; red[wid + 4] = ss; }
    __syncthreads();
    if (tid == 0) {
        float S  = (red[0] + red[1]) + (red[2] + red[3]);
        float SS = (red[4] + red[5]) + (red[6] + red[7]);
        float mean = S * (1.f / 16384.f);
        float var  = SS * (1.f / 16384.f) - mean * mean;
        stats[bg * 2]     = mean;
        stats[bg * 2 + 1] = rsqrtf(var + kEps);
    }
}

// ---------------- Kernel 1b: proj_w -> bf16 ----------------
__global__ __launch_bounds__(256) void prep_k(const float* __restrict__ w,
                                              unsigned short* __restrict__ wb) {
    int i = (blockIdx.x * 256 + threadIdx.x) * 4;
    float4 v = *(const float4*)(w + i);
    wb[i + 0] = f2bf(v.x); wb[i + 1] = f2bf(v.y);
    wb[i + 2] = f2bf(v.z); wb[i + 3] = f2bf(v.w);
}

// ---------------- Kernel 2: kv = silu(nd) @ nd_w^T + nd_b (bf16 + bf16^T) ----
__global__ __launch_bounds__(256) void kv_k(const float* __restrict__ nd,
                                            const float* __restrict__ nd_w,
                                            const float* __restrict__ nd_b,
                                            unsigned short* __restrict__ kv_bf,
                                            unsigned short* __restrict__ kvT_bf) {
    __shared__ float s_lds[8][256];
    __shared__ float w_lds[128][68];
    __shared__ float t_lds[8][129];
    int b = blockIdx.y;
    int l0 = blockIdx.x * 8;
    int tid = threadIdx.x;
    const float4* ndp = (const float4*)(nd + ((size_t)b * kL + l0) * kND);
#pragma unroll
    for (int r = 0; r < 2; r++) {
        int idx = tid + r * 256;
        int row = idx >> 6;
        int c4 = idx & 63;
        float4 v = ndp[row * 64 + c4];
        v.x = v.x / (1.f + __expf(-v.x));
        v.y = v.y / (1.f + __expf(-v.y));
        v.z = v.z / (1.f + __expf(-v.z));
        v.w = v.w / (1.f + __expf(-v.w));
        *(float4*)&s_lds[row][c4 * 4] = v;
    }
    float acc[4] = {0.f, 0.f, 0.f, 0.f};
    int lr = tid >> 5;
    int oq = tid & 31;
    for (int d0 = 0; d0 < kND; d0 += 64) {
        __syncthreads();
#pragma unroll
        for (int r = 0; r < 8; r++) {
            int idx = tid + r * 256;
            int row = idx >> 4;
            int c4 = idx & 15;
            float4 v = ((const float4*)(nd_w + (size_t)row * kND + d0))[c4];
            *(float4*)&w_lds[row][c4 * 4] = v;
        }
        __syncthreads();
        for (int dd = 0; dd < 64; dd += 4) {
            float4 sv = *(const float4*)&s_lds[lr][d0 + dd];
#pragma unroll
            for (int j = 0; j < 4; j++) {
                float4 wv = *(const float4*)&w_lds[oq + 32 * j][dd];
                acc[j] += sv.x * wv.x + sv.y * wv.y + sv.z * wv.z + sv.w * wv.w;
            }
        }
    }
#pragma unroll
    for (int j = 0; j < 4; j++) {
        int o = oq + 32 * j;
        float vout = acc[j] + nd_b[o];
        kv_bf[((size_t)b * kL + l0 + lr) * kC + o] = f2bf(vout);
        t_lds[lr][o] = vout;
    }
    __syncthreads();
    {
        int o = tid >> 1, lh = (tid & 1) * 4;
        unsigned long long pk = 0;
#pragma unroll
        for (int i = 0; i < 4; i++)
            pk |= (unsigned long long)f2bf(t_lds[lh + i][o]) << (16 * i);
        *(unsigned long long*)(kvT_bf + ((size_t)b * kC + o) * kL + l0 + lh) = pk;
    }
}

// ---------------- Kernel 3: q = (GN(x))^T @ q_w^T + q_b  (bf16 MFMA) -------
__global__ __launch_bounds__(256) void qproj_k(const float* __restrict__ x,
                                               const float* __restrict__ stats,
                                               const float* __restrict__ gamma,
                                               const float* __restrict__ beta,
                                               const float* __restrict__ q_w,
                                               const float* __restrict__ q_b,
                                               unsigned short* __restrict__ q_bf) {
    __shared__ __align__(16) unsigned short smem[17408];  // [128][136] bf16
    __shared__ float gab[256];                            // ga[128], be[128]
    const int b = blockIdx.y;
    const int n0 = blockIdx.x * 128;
    const int tid = threadIdx.x;
    const int wave = tid >> 6, lane = tid & 63;
    const int lrow = lane & 31, hi = lane >> 5;

    if (tid < 128) {
        float mean = stats[(b * kG + (tid >> 2)) * 2];
        float rstd = stats[(b * kG + (tid >> 2)) * 2 + 1];
        float ga = gamma[tid] * rstd;
        gab[tid] = ga;
        gab[128 + tid] = beta[tid] - mean * ga;
    }
    // stage q_w as bf16 [o][c], padded stride 136
#pragma unroll
    for (int r = 0; r < 16; r++) {
        int idx = tid + r * 256;            // 4096 float4 = 128x32
        int row = idx >> 5, c4 = idx & 31;
        float4 v = ((const float4*)q_w)[idx];
        unsigned int lo = (unsigned int)f2bf(v.x) | ((unsigned int)f2bf(v.y) << 16);
        unsigned int h2 = (unsigned int)f2bf(v.z) | ((unsigned int)f2bf(v.w) << 16);
        *(uint2*)&smem[row * 136 + c4 * 4] = make_uint2(lo, h2);
    }
    __syncthreads();

    // A fragments: hn[n][c] with GN fused, straight from global
    sv8 qa[8];
    {
        const float* xp = x + (size_t)b * kC * kHW + n0 + wave * 32 + lrow;
#pragma unroll
        for (int kc = 0; kc < 8; kc++) {
            int cb = kc * 16 + hi * 8;
            float4 g0 = *(const float4*)&gab[cb];
            float4 g1 = *(const float4*)&gab[cb + 4];
            float4 e0 = *(const float4*)&gab[128 + cb];
            float4 e1 = *(const float4*)&gab[128 + cb + 4];
            sv8 a;
            a[0] = (short)f2bf(xp[(size_t)(cb + 0) * kHW] * g0.x + e0.x);
            a[1] = (short)f2bf(xp[(size_t)(cb + 1) * kHW] * g0.y + e0.y);
            a[2] = (short)f2bf(xp[(size_t)(cb + 2) * kHW] * g0.z + e0.z);
            a[3] = (short)f2bf(xp[(size_t)(cb + 3) * kHW] * g0.w + e0.w);
            a[4] = (short)f2bf(xp[(size_t)(cb + 4) * kHW] * g1.x + e1.x);
            a[5] = (short)f2bf(xp[(size_t)(cb + 5) * kHW] * g1.y + e1.y);
            a[6] = (short)f2bf(xp[(size_t)(cb + 6) * kHW] * g1.z + e1.z);
            a[7] = (short)f2bf(xp[(size_t)(cb + 7) * kHW] * g1.w + e1.w);
            qa[kc] = a;
        }
    }

    f32x16 dacc[4];
#pragma unroll
    for (int ot = 0; ot < 4; ot++)
#pragma unroll
        for (int r = 0; r < 16; r++) dacc[ot][r] = 0.f;
#pragma unroll
    for (int ot = 0; ot < 4; ot++) {
        const unsigned short* brow = smem + (ot * 32 + lrow) * 136 + hi * 8;
#pragma unroll
        for (int kc = 0; kc < 8; kc++)
            dacc[ot] = __builtin_amdgcn_mfma_f32_32x32x16_bf16(
                           qa[kc], *(const sv8*)(brow + kc * 16), dacc[ot], 0, 0, 0);
    }
    __syncthreads();   // all B-reads done; reuse smem as q[n][o] transpose

#pragma unroll
    for (int ot = 0; ot < 4; ot++) {
        int o = ot * 32 + lrow;
        float qb = q_b[o];
#pragma unroll
        for (int r = 0; r < 16; r++) {
            int n_loc = wave * 32 + (r & 3) + 8 * (r >> 2) + 4 * hi;
            smem[n_loc * 136 + o] = f2bf((dacc[ot][r] + qb) * kScale);
        }
    }
    __syncthreads();
#pragma unroll
    for (int r = 0; r < 8; r++) {
        int idx = tid + r * 256;            // 2048 uint4 = 128 rows x 16
        int n = idx >> 4, ch = idx & 15;
        *(uint4*)(q_bf + ((size_t)b * kHW + n0 + n) * kC + ch * 8) =
            *(const uint4*)&smem[n * 136 + ch * 8];
    }
}

// ---------------- Kernel 4: MFMA attention + proj + residual ----------------
// Block: 128 Q-rows x 1 batch, 4 waves x 32 rows. Swapped QK^T (mfma(K,Q)):
// P stays in registers. kv/kvT double-buffered in LDS, staged via
// global_load_lds (direct-to-LDS, no VGPR round-trip, no ds_writes) with
// pre-swizzled per-lane SOURCE addresses + linear LDS dest (write-permute
// == read-XOR involution). One barrier per tile; its automatic vmcnt drain
// is free (loads issued a full compute-phase earlier, kv is L2-resident).
// XCD-aware block swizzle: each XCD's L2 serves only 2 batches' kv.
__global__ __launch_bounds__(256, 2) void attn_k(
    const unsigned short* __restrict__ qb,    // [B][HW][C] bf16, pre-scaled
    const unsigned short* __restrict__ kvb,   // [B][L][C] bf16
    const unsigned short* __restrict__ kvtb,  // [B][C][L] bf16
    const unsigned short* __restrict__ pwb,   // [C][C] bf16 (o-major)
    const float* __restrict__ proj_b,
    const float* __restrict__ x,
    float* __restrict__ out)
{
    __shared__ __align__(16) char smem[66048];
    // kvA[2]: [0,16384),[16384,32768)    : [64 l][128 c] bf16, ch16 ^= (l&15)
    // kvT[2]: [32768,49152),[49152,65536): [128 c][64 l] bf16, ch16 ^= (c&7)
    // rs    : [65536,66048): 4 waves x 32 f32 (1/rowsum)
    // epilogue o_lds: ushort [128][136] at 0 (aliases; barrier-guarded)

    const int flat = blockIdx.y * gridDim.x + blockIdx.x;   // 0..511
    const int b  = ((flat & 7) << 1) | ((flat >> 3) & 1);   // XCD-clustered
    const int n0 = (flat >> 4) * 128;
    const int tid = threadIdx.x;
    const int wave = tid >> 6;
    const int lane = tid & 63;
    const int lrow = lane & 31;
    const int hi = lane >> 5;
    const int swzA = (lrow & 15) << 4;
    const int swzT = (lrow & 7) << 4;

    // Q fragments (serve as the B-operand of the swapped QK^T: same lane map)
    sv8 qa[8];
    {
        const unsigned short* qrow =
            qb + ((size_t)b * kHW + n0 + wave * 32 + lrow) * kC + hi * 8;
#pragma unroll
        for (int kc = 0; kc < 8; kc++)
            qa[kc] = *(const sv8*)(qrow + kc * 16);
    }

    f32x16 oacc[4];
#pragma unroll
    for (int ct = 0; ct < 4; ct++)
#pragma unroll
        for (int r = 0; r < 16; r++) oacc[ct][r] = 0.f;
    float rsumv = 0.f;

    const unsigned short* kvB  = kvb  + (size_t)b * kL * kC;
    const unsigned short* kvtB = kvtb + (size_t)b * kC * kL;

    // ---- staging: 8 global_load_lds per thread per tile (macro, no lambdas)
#define STAGE_TILE(tt) do {                                                     \
        int l0s = (tt) << 6;                                                    \
        char* dA = smem + (((tt) & 1) * 16384);                                 \
        char* dT = smem + 32768 + (((tt) & 1) * 16384);                         \
        _Pragma("unroll")                                                       \
        for (int i = 0; i < 4; i++) {                                           \
            int l = wave * 16 + i * 4 + (lane >> 4);                            \
            int ch = lane & 15;                                                 \
            const unsigned short* gs =                                          \
                kvB + (size_t)(l0s + l) * kC + ((ch ^ (l & 15)) * 8);           \
            GLOAD_LDS16(gs, dA + (wave * 4 + i) * 1024);                        \
        }                                                                       \
        _Pragma("unroll")                                                       \
        for (int i = 0; i < 4; i++) {                                           \
            int c = wave * 32 + i * 8 + (lane >> 3);                            \
            int ch = lane & 7;                                                  \
            const unsigned short* gs =                                          \
                kvtB + (size_t)c * kL + l0s + ((ch ^ (c & 7)) * 8);             \
            GLOAD_LDS16(gs, dT + (wave * 4 + i) * 1024);                        \
        }                                                                       \
    } while (0)

    STAGE_TILE(0);
    __syncthreads();           // barrier drains vmcnt -> tile 0 visible

    for (int t = 0; t < 8; t++) {
        const char* bufA = smem + (t & 1) * 16384;
        const char* bufT = smem + 32768 + (t & 1) * 16384;
        if (t < 7) STAGE_TILE(t + 1);     // in flight across the compute phase

        // ---- swapped QK^T: S[l][n] = mfma(A=kv, B=q); exp in registers ----
        unsigned int pka[2][4], pkb[2][4];
#pragma unroll
        for (int ls = 0; ls < 2; ls++) {
            f32x16 s;
#pragma unroll
            for (int r = 0; r < 16; r++) s[r] = 0.f;
            const char* arow = bufA + (ls * 32 + lrow) * 256;
            __builtin_amdgcn_s_setprio(1);
#pragma unroll
            for (int kc = 0; kc < 8; kc++)
                s = __builtin_amdgcn_mfma_f32_32x32x16_bf16(
                        *(const sv8*)(arow + ((kc * 32 + hi * 16) ^ swzA)),
                        qa[kc], s, 0, 0, 0);
            __builtin_amdgcn_s_setprio(0);
            float p[16];
#pragma unroll
            for (int r = 0; r < 16; r++) {
                p[r] = __expf(s[r]);              // max-free: |logit| << 1
                rsumv += p[r];
            }
#pragma unroll
            for (int g = 0; g < 4; g++) {
                pka[ls][g] = pack2(p[4 * g + 0], p[4 * g + 1]);
                pkb[ls][g] = pack2(p[4 * g + 2], p[4 * g + 3]);
            }
        }
        // ---- assemble PV A-fragments: lane n holds P[n][l], l=kk*16+hi*8+j.
        sv8 pv[4];
#pragma unroll
        for (int kk = 0; kk < 4; kk++) {
            int ls = kk >> 1;
            unsigned int a_lo = pka[ls][(kk & 1) * 2], a_hi = pka[ls][(kk & 1) * 2 + 1];
            unsigned int b_lo = pkb[ls][(kk & 1) * 2], b_hi = pkb[ls][(kk & 1) * 2 + 1];
            unsigned int own_a = hi ? a_hi : a_lo;
            unsigned int own_b = hi ? b_hi : b_lo;
            unsigned int rcv_a = (unsigned int)__shfl_xor((int)(hi ? a_lo : a_hi), 32, 64);
            unsigned int rcv_b = (unsigned int)__shfl_xor((int)(hi ? b_lo : b_hi), 32, 64);
            iv4 w;
            w[0] = (int)(hi ? rcv_a : own_a);
            w[1] = (int)(hi ? rcv_b : own_b);
            w[2] = (int)(hi ? own_a : rcv_a);
            w[3] = (int)(hi ? own_b : rcv_b);
            pv[kk] = __builtin_bit_cast(sv8, w);
        }
        // ---- PV: O[n][c] += P[n][l] * kv[l][c]; B from swizzled kvT ----
        __builtin_amdgcn_s_setprio(1);
#pragma unroll
        for (int ct = 0; ct < 4; ct++) {
            const char* rowp = bufT + (ct * 32 + lrow) * 128;
#pragma unroll
            for (int kk = 0; kk < 4; kk++)
                oacc[ct] = __builtin_amdgcn_mfma_f32_32x32x16_bf16(
                               pv[kk],
                               *(const sv8*)(rowp + ((kk * 32 + hi * 16) ^ swzT)),
                               oacc[ct], 0, 0, 0);
        }
        __builtin_amdgcn_s_setprio(0);

        __syncthreads();   // drains vmcnt (t+1 loads landed) + guards dbuf swap
    }

    // ---- softmax denominators: lane n has column-sum over its 32 l's ----
    float total = rsumv + __shfl_xor(rsumv, 32, 64);
    float* rs = (float*)(smem + 65536) + wave * 32;
    rs[lrow] = 1.0f / total;                 // both halves write same value
    float rinv[16];
#pragma unroll
    for (int r = 0; r < 16; r++)
        rinv[r] = rs[(r & 3) + 8 * (r >> 2) + 4 * hi];

    unsigned short* o_lds = (unsigned short*)smem;   // [128][136]
    __syncthreads();
    // normalized O -> o_lds bf16 [128 n][136 c]  (per-wave row-disjoint)
#pragma unroll
    for (int ct = 0; ct < 4; ct++)
#pragma unroll
        for (int r = 0; r < 16; r++) {
            int n = wave * 32 + (r & 3) + 8 * (r >> 2) + 4 * hi;
            o_lds[n * 136 + ct * 32 + lrow] = f2bf(oacc[ct][r] * rinv[r]);
        }
    // proj: D[n][o] = O[n][c] * pw[o][c]
    sv8 oa[8];
    {
        const unsigned short* orow = o_lds + (wave * 32 + lrow) * 136 + hi * 8;
#pragma unroll
        for (int kc = 0; kc < 8; kc++) oa[kc] = *(const sv8*)(orow + kc * 16);
    }
    f32x16 dacc[4];
#pragma unroll
    for (int ot = 0; ot < 4; ot++)
#pragma unroll
        for (int r = 0; r < 16; r++) dacc[ot][r] = 0.f;
#pragma unroll
    for (int ot = 0; ot < 4; ot++) {
        const unsigned short* brow = pwb + (ot * 32 + lrow) * kC + hi * 8;
#pragma unroll
        for (int kc = 0; kc < 8; kc++)
            dacc[ot] = __builtin_amdgcn_mfma_f32_32x32x16_bf16(
                           oa[kc], *(const sv8*)(brow + kc * 16), dacc[ot], 0, 0, 0);
    }
    // D -> o_lds bf16 [128 n][136 o] (own rows only; reads already in regs)
#pragma unroll
    for (int ot = 0; ot < 4; ot++)
#pragma unroll
        for (int r = 0; r < 16; r++) {
            int n = wave * 32 + (r & 3) + 8 * (r >> 2) + 4 * hi;
            o_lds[n * 136 + ot * 32 + lrow] = f2bf(dacc[ot][r]);
        }
    __syncthreads();
    // epilogue: out[b][o][n0+n] = D[n][o] + proj_b[o] + x  (coalesced)
#pragma unroll 4
    for (int it = 0; it < 64; it++) {
        int idx = it * 256 + tid;
        int o = idx >> 7, n = idx & 127;
        size_t gi = ((size_t)b * kC + o) * kHW + n0 + n;
        out[gi] = bf2f(o_lds[n * 136 + o]) + proj_b[o] + x[gi];
    }
#undef STAGE_TILE
}

extern "C" void kernel_launch(void* const* d_in, const int* in_sizes, int n_in,
                              void* d_out, int out_size, void* d_ws, size_t ws_size,
                              hipStream_t stream) {
    const float* x      = (const float*)d_in[0];
    const float* nd     = (const float*)d_in[1];
    const float* gamma  = (const float*)d_in[2];
    const float* beta   = (const float*)d_in[3];
    const float* q_w    = (const float*)d_in[4];
    const float* q_b    = (const float*)d_in[5];
    const float* nd_w   = (const float*)d_in[6];
    const float* nd_b   = (const float*)d_in[7];
    const float* proj_w = (const float*)d_in[8];
    const float* proj_b = (const float*)d_in[9];
    float* out = (float*)d_out;

    float* stats          = (float*)d_ws;                  // 1024 f32
    unsigned short* pwb   = (unsigned short*)(stats + 1024);       // 16384
    unsigned short* kv_bf = pwb + 16384;                   // 1,048,576
    unsigned short* kvT_bf = kv_bf + (size_t)kB * kL * kC; // 1,048,576
    unsigned short* q_bf  = kvT_bf + (size_t)kB * kL * kC; // 8,388,608

    gn_stats_k<<<dim3(kB * kG), dim3(256), 0, stream>>>(x, stats);
    prep_k<<<dim3(16), dim3(256), 0, stream>>>(proj_w, pwb);
    kv_k<<<dim3(kL / 8, kB), dim3(256), 0, stream>>>(nd, nd_w, nd_b, kv_bf, kvT_bf);
    qproj_k<<<dim3(kHW / 128, kB), dim3(256), 0, stream>>>(x, stats, gamma, beta, q_w, q_b, q_bf);
    attn_k<<<dim3(kHW / 128, kB), dim3(256), 0, stream>>>(q_bf, kv_bf, kvT_bf, pwb,
                                                          proj_b, x, out);
}